// Round 1
// baseline (354.080 us; speedup 1.0000x reference)
//
#include <hip/hip_runtime.h>
#include <stdint.h>
#include <stddef.h>

// ---------------------------------------------------------------------------
// CausalSelfAttention forward, MI355X/gfx950.
// Pipeline: cvt(fp32->bf16) -> GEMM1(qkv) -> norm+rope+transpose ->
//           attn_fwd2 (flash, fixed-max softmax, LDS-staged K/V) ->
//           GEMM2(out proj, fp32)
// R4: attention is VMEM-demand-bound (~6 TB/s ceiling, measured R1/R2/R3).
//     Block of 8 waves stages each 32-key K/V tile into LDS ONCE via
//     global_load_lds (source-address permutation puts LDS in exact
//     fragment-read order -> conflict-free contiguous ds_read_b128),
//     double-buffered, one barrier/tile, stage issued after the barrier so
//     it overlaps compute. 16 frag-tiles share each staged tile: global
//     traffic per frag-tile drops 6 KB -> 0.75 KB (8x vs R2).
//     Mirrored q-frags (qp and 15-qp) keep per-block work uniform.
// R5 (this round): infra failure last round -> re-establish baseline.
//     Only change: bijective XCD-aware tile swizzle in gemm_bt (T1).
//     Pure blockIdx->tile permutation (nwg%8==0 for both launches), zero
//     correctness risk; expect small L2-locality gain on the GEMMs.
// ---------------------------------------------------------------------------

typedef __attribute__((ext_vector_type(8))) __bf16 bf16x8;
typedef __attribute__((ext_vector_type(4))) __bf16 bf16x4;
typedef __attribute__((ext_vector_type(4))) float  f32x4;

#define NB 2
#define NT 2048
#define NC 1536
#define NH 16
#define ND 96
#define NQKV 4608          // 3*NC
#define NM 4096            // NB*NT

static __device__ __forceinline__ float fexp2(float x) {
#if __has_builtin(__builtin_amdgcn_exp2f)
  return __builtin_amdgcn_exp2f(x);
#else
  return exp2f(x);
#endif
}

// async global->LDS, 16B per lane; LDS dest = wave-uniform base + lane*16
static __device__ __forceinline__ void g2lds16(const void* g, void* l) {
  __builtin_amdgcn_global_load_lds(
      (const __attribute__((address_space(1))) void*)g,
      (__attribute__((address_space(3))) void*)l, 16, 0, 0);
}

// ---------------------------------------------------------------------------
// fp32 -> bf16 conversion (vectorized 4-wide)
// ---------------------------------------------------------------------------
__global__ __launch_bounds__(256) void cvt_f32_bf16(
    const float4* __restrict__ src, bf16x4* __restrict__ dst, int n4) {
  int i = blockIdx.x * 256 + threadIdx.x;
  if (i < n4) {
    float4 v = src[i];
    bf16x4 o;
    o[0] = (__bf16)v.x; o[1] = (__bf16)v.y;
    o[2] = (__bf16)v.z; o[3] = (__bf16)v.w;
    dst[i] = o;
  }
}

// ---------------------------------------------------------------------------
// GEMM: C[m][n] = sum_k A[m][k] * B[n][k]   (A: MxK bf16, B: NxK bf16)
// 128x128 tile, BK=32, 4 waves (2x2), each wave 64x64 via 4x4 mfma 16x16x32.
// R5: XCD-aware bijective tile swizzle (T1) — each XCD owns a contiguous
// row-major tile range -> neighbor tiles sharing A-panels hit the same L2.
// ---------------------------------------------------------------------------
__global__ __launch_bounds__(256) void gemm_bt(
    const __bf16* __restrict__ A, const __bf16* __restrict__ Bw,
    float* __restrict__ Cf, __bf16* __restrict__ Cb, int M, int N, int K) {
  __shared__ __align__(16) __bf16 Al[128 * 32];
  __shared__ __align__(16) __bf16 Bl[128 * 32];
  const int tid = threadIdx.x;
  const int l   = tid & 63;
  const int w   = tid >> 6;

  // T1 swizzle: nwg % 8 == 0 for both launches (1152, 384) -> bijective.
  const int nwg = gridDim.x * gridDim.y;
  const int lid = blockIdx.y * gridDim.x + blockIdx.x;
  const int cpx = nwg >> 3;
  const int swz = (lid & 7) * cpx + (lid >> 3);
  const int m0  = (swz / gridDim.x) * 128;
  const int n0  = (swz % gridDim.x) * 128;

  const int wm  = (w >> 1) * 64;
  const int wn  = (w & 1) * 64;
  const int lm  = l & 15;
  const int lq  = l >> 4;
  const int srow = l >> 2;          // row within wave chunk
  const int scol = (l & 3) * 8;     // bf16 element offset in row

  f32x4 acc[4][4] = {};

  for (int k0 = 0; k0 < K; k0 += 32) {
#pragma unroll
    for (int rd = 0; rd < 2; ++rd) {
      const int row = rd * 64 + w * 16 + srow;
      const int lof = rd * 4096 + w * 1024;
      g2lds16(A  + (size_t)(m0 + row) * K + k0 + scol, (char*)Al + lof);
      g2lds16(Bw + (size_t)(n0 + row) * K + k0 + scol, (char*)Bl + lof);
    }
    __syncthreads();
    bf16x8 af[4], bfr[4];
#pragma unroll
    for (int mi = 0; mi < 4; ++mi)
      af[mi] = *(const bf16x8*)(Al + (wm + mi * 16 + lm) * 32 + lq * 8);
#pragma unroll
    for (int ni = 0; ni < 4; ++ni)
      bfr[ni] = *(const bf16x8*)(Bl + (wn + ni * 16 + lm) * 32 + lq * 8);
#pragma unroll
    for (int mi = 0; mi < 4; ++mi)
#pragma unroll
      for (int ni = 0; ni < 4; ++ni)
        acc[mi][ni] = __builtin_amdgcn_mfma_f32_16x16x32_bf16(
            af[mi], bfr[ni], acc[mi][ni], 0, 0, 0);
    __syncthreads();
  }

  // epilogue: C/D layout col=lane&15, row=(lane>>4)*4+r  (m89/m91 verified)
  const int r0 = lq * 4;
#pragma unroll
  for (int mi = 0; mi < 4; ++mi)
#pragma unroll
    for (int ni = 0; ni < 4; ++ni)
#pragma unroll
      for (int r = 0; r < 4; ++r) {
        const size_t row = (size_t)(m0 + wm + mi * 16 + r0 + r);
        const size_t col = (size_t)(n0 + wn + ni * 16 + lm);
        if (Cf) Cf[row * N + col] = acc[mi][ni][r];
        else    Cb[row * N + col] = (__bf16)acc[mi][ni][r];
      }
}

// ---------------------------------------------------------------------------
// qk RMS-norm + 3D RoPE + layout transform.
// ---------------------------------------------------------------------------
static __device__ __forceinline__ float rope_one(float v, float p, int d,
                                                 const float* c3) {
  const int a  = d >> 5;        // which of 3 coord axes (d3=32)
  const int j  = d & 31;
  const int jj = j & 15;        // half=16
  const float invf = fexp2((float)jj * -0.8304820237218406f);
  const float ang  = c3[a] * invf;
  float sn, cs;
  __sincosf(ang, &sn, &cs);
  return (j < 16) ? (v * cs - p * sn) : (v * cs + p * sn);
}

__global__ __launch_bounds__(256) void normrope_kernel(
    const __bf16* __restrict__ qkv, const float* __restrict__ coords,
    const int* __restrict__ ttype, const float* __restrict__ qsc,
    const float* __restrict__ ksc, __bf16* __restrict__ qo,
    __bf16* __restrict__ ko, __bf16* __restrict__ vo) {
  const int l   = threadIdx.x & 63;
  const int w   = threadIdx.x >> 6;
  const int rid = blockIdx.x * 4 + w;       // (b*T+t)*H + h
  const int h   = rid & (NH - 1);
  const int bt  = rid >> 4;
  const int t   = bt & (NT - 1);
  const int b   = bt >> 11;                 // T = 2048
  const __bf16* base = qkv + (size_t)bt * NQKV + h * ND;
  const float*  c3   = coords + (size_t)bt * 3;
  const bool rope    = ttype[bt] > 0;
  const size_t bh    = (size_t)(b * NH + h);

  // ---- q ----
  {
    float x0 = (float)base[l];
    float x1 = (l < 32) ? (float)base[64 + l] : 0.f;
    float ss = x0 * x0 + x1 * x1;
#pragma unroll
    for (int off = 1; off < 64; off <<= 1) ss += __shfl_xor(ss, off, 64);
    const float rn = rsqrtf(ss * (1.f / 96.f) + 1e-6f);
    x0 *= rn * qsc[l];
    if (l < 32) x1 *= rn * qsc[64 + l];
    const float p0 = __shfl_xor(x0, 16, 64);
    const float p1 = __shfl_xor(x1, 16, 64);
    if (rope) {
      x0 = rope_one(x0, p0, l, c3);
      if (l < 32) x1 = rope_one(x1, p1, 64 + l, c3);
    }
    __bf16* dst = qo + (bh * NT + t) * ND;
    dst[l] = (__bf16)x0;
    if (l < 32) dst[64 + l] = (__bf16)x1;
  }
  // ---- k ----
  {
    float x0 = (float)base[NC + l];
    float x1 = (l < 32) ? (float)base[NC + 64 + l] : 0.f;
    float ss = x0 * x0 + x1 * x1;
#pragma unroll
    for (int off = 1; off < 64; off <<= 1) ss += __shfl_xor(ss, off, 64);
    const float rn = rsqrtf(ss * (1.f / 96.f) + 1e-6f);
    x0 *= rn * ksc[l];
    if (l < 32) x1 *= rn * ksc[64 + l];
    const float p0 = __shfl_xor(x0, 16, 64);
    const float p1 = __shfl_xor(x1, 16, 64);
    if (rope) {
      x0 = rope_one(x0, p0, l, c3);
      if (l < 32) x1 = rope_one(x1, p1, 64 + l, c3);
    }
    __bf16* dst = ko + (bh * NT + t) * ND;
    dst[l] = (__bf16)x0;
    if (l < 32) dst[64 + l] = (__bf16)x1;
  }
  // ---- v (transpose only) ----
  {
    vo[(bh * ND + l) * NT + t] = base[2 * NC + l];
    if (l < 32) vo[(bh * ND + 64 + l) * NT + t] = base[2 * NC + 64 + l];
  }
}

// ---------------------------------------------------------------------------
// Flash attention with LDS-staged K/V, fixed-max softmax.
// q,k: (B,H,T,D) bf16; vT: (B,H,D,T) bf16; out: (B,T,H,D)=(B*T,C) bf16.
// Grid (8, B*H), block = 8 waves (512 thr). Wave w owns two mirrored 16-row
// frags: q0L = qp*128+w*16, q0H = (15-qp)*128+w*16 -> uniform block work.
// Per 32-key tile: stage K(6KB)+vT(6KB) -> LDS via g2lds16 with source-addr
// permutation so LDS is in fragment-read order (each frag read = 64 lanes
// reading a contiguous 1KB span; conflict-free). Double-buffered; stage for
// kt+1 issued after the barrier -> overlaps compute of kt.
// ---------------------------------------------------------------------------
static __device__ __forceinline__ void attn_tile(
    const bf16x8 (&aq)[3], const bf16x8 (&bk)[2][3], int q0r, int n0,
    int lm, int lq, f32x4& lsum, __bf16* pbase /* 16 rows x 40 */) {
  f32x4 s[2];
#pragma unroll
  for (int nt = 0; nt < 2; ++nt) {
    f32x4 a = {};
#pragma unroll
    for (int c = 0; c < 3; ++c)
      a = __builtin_amdgcn_mfma_f32_16x16x32_bf16(aq[c], bk[nt][c], a, 0, 0, 0);
    s[nt] = a;
  }
  if (n0 + 31 > q0r) {   // diagonal-straddling tile: causal mask
#pragma unroll
    for (int nt = 0; nt < 2; ++nt)
#pragma unroll
      for (int r = 0; r < 4; ++r)
        if (n0 + nt * 16 + lm > q0r + lq * 4 + r) s[nt][r] = -1e30f;
  }
  const float cl = 0.10206207261596575f * 1.4426950408889634f;
#pragma unroll
  for (int nt = 0; nt < 2; ++nt)
#pragma unroll
    for (int r = 0; r < 4; ++r)
      s[nt][r] = fexp2((s[nt][r] - 96.0f) * cl);
#pragma unroll
  for (int r = 0; r < 4; ++r) lsum[r] += s[0][r] + s[1][r];
#pragma unroll
  for (int nt = 0; nt < 2; ++nt)
#pragma unroll
    for (int r = 0; r < 4; ++r)
      pbase[(lq * 4 + r) * 40 + nt * 16 + lm] = (__bf16)s[nt][r];
}

__global__ __launch_bounds__(512) void attn_fwd2(
    const __bf16* __restrict__ q, const __bf16* __restrict__ k,
    const __bf16* __restrict__ vt, __bf16* __restrict__ out) {
  __shared__ __align__(16) char KV[2][12288];        // [buf][K 6KB | V 6KB]
  __shared__ __align__(16) __bf16 plds[8][2][16][40];
  const int tid = threadIdx.x;
  const int l   = tid & 63;
  const int w   = tid >> 6;          // 0..7
  const int bh  = blockIdx.y;
  const int qp  = blockIdx.x;        // 0..7
  const int lm  = l & 15;
  const int lq  = l >> 4;
  const int q0L = qp * 128 + w * 16;
  const int q0H = (15 - qp) * 128 + w * 16;
  const int nktLw = qp * 4 + (w >> 1) + 1;          // causal tiles, frag L
  const int nktHw = (15 - qp) * 4 + (w >> 1) + 1;   // causal tiles, frag H
  const int nkt   = (15 - qp) * 4 + 4;              // block loop bound
  const __bf16* qh = q  + (size_t)bh * NT * ND;
  const __bf16* kh = k  + (size_t)bh * NT * ND;
  const __bf16* vh = vt + (size_t)bh * ND * NT;
  __bf16* pbL = &plds[w][0][0][0];
  __bf16* pbH = &plds[w][1][0][0];

  // stage tile at key n0 into buf. LDS K layout: chunk (nt*3+c)*64 + lm*4+lq
  // holds K[n0+nt*16+lm][c*32+lq*8 ..+7]; V chunk dt*64+lm*4+lq holds
  // vT[dt*16+lm][n0+lq*8 ..+7]. Wave-uniform LDS bases, all lanes active.
  auto stage = [&](int n0, char* buf) {
    if (w < 6) {
      const int nt = w / 3, c = w - nt * 3;
      g2lds16(kh + (size_t)(n0 + nt * 16 + (l >> 2)) * ND + c * 32 + (l & 3) * 8,
              buf + w * 1024);
    } else {
      const int v = w - 6;
      g2lds16(vh + (size_t)(v * 16 + (l >> 2)) * NT + n0 + (l & 3) * 8,
              buf + 6144 + v * 1024);
    }
    if (w < 4) {
      const int v = 2 + w;
      g2lds16(vh + (size_t)(v * 16 + (l >> 2)) * NT + n0 + (l & 3) * 8,
              buf + 6144 + v * 1024);
    }
  };

  bf16x8 aqL[3], aqH[3];
#pragma unroll
  for (int c = 0; c < 3; ++c) {
    aqL[c] = *(const bf16x8*)(qh + (size_t)(q0L + lm) * ND + c * 32 + lq * 8);
    aqH[c] = *(const bf16x8*)(qh + (size_t)(q0H + lm) * ND + c * 32 + lq * 8);
  }

  f32x4 oL[6] = {}, oH[6] = {};
  f32x4 lsL = {}, lsH = {};
  const int ji = (lm * 4 + lq) * 16;   // this lane's chunk byte offset

  stage(0, KV[0]);
  for (int kt = 0; kt < nkt; ++kt) {
    __syncthreads();                   // drains stage(kt); all waves done kt-1
    if (kt + 1 < nkt) stage((kt + 1) * 32, KV[(kt + 1) & 1]);
    const char* Kc = KV[kt & 1];
    const char* Vc = KV[kt & 1] + 6144;
    const int n0 = kt * 32;
    bf16x8 bk[2][3];
#pragma unroll
    for (int nt = 0; nt < 2; ++nt)
#pragma unroll
      for (int c = 0; c < 3; ++c)
        bk[nt][c] = *(const bf16x8*)(Kc + (nt * 3 + c) * 1024 + ji);
    const bool doL = kt < nktLw;       // wave-uniform
    const bool doH = kt < nktHw;
    if (doL) attn_tile(aqL, bk, q0L, n0, lm, lq, lsL, pbL);
    if (doH) attn_tile(aqH, bk, q0H, n0, lm, lq, lsH, pbH);
    bf16x8 apL = {}, apH = {};
    if (doL) apL = *(const bf16x8*)(pbL + lm * 40 + lq * 8);
    if (doH) apH = *(const bf16x8*)(pbH + lm * 40 + lq * 8);
#pragma unroll
    for (int dt = 0; dt < 6; ++dt) {
      bf16x8 bv = *(const bf16x8*)(Vc + dt * 1024 + ji);
      if (doL) oL[dt] = __builtin_amdgcn_mfma_f32_16x16x32_bf16(apL, bv, oL[dt], 0, 0, 0);
      if (doH) oH[dt] = __builtin_amdgcn_mfma_f32_16x16x32_bf16(apH, bv, oH[dt], 0, 0, 0);
    }
  }

  // epilogue: out[(b*T+t), h*96+d] for both frags
  const int b = bh >> 4, h = bh & 15;
#pragma unroll
  for (int f = 0; f < 2; ++f) {
    const f32x4* o = f ? oH : oL;
    const f32x4& ls = f ? lsH : lsL;
    const int q0 = f ? q0H : q0L;
    float rl[4];
#pragma unroll
    for (int r = 0; r < 4; ++r) {
      float v = ls[r];
#pragma unroll
      for (int off = 1; off < 16; off <<= 1) v += __shfl_xor(v, off, 64);
      rl[r] = 1.f / v;
    }
#pragma unroll
    for (int dt = 0; dt < 6; ++dt)
#pragma unroll
      for (int r = 0; r < 4; ++r) {
        const int t = q0 + lq * 4 + r;
        out[((size_t)(b * NT + t)) * NC + h * ND + dt * 16 + lm] =
            (__bf16)(o[dt][r] * rl[r]);
      }
  }
}

// ---------------------------------------------------------------------------
// workspace layout (bytes); attn-out aliases xb (dead after GEMM1)
// ---------------------------------------------------------------------------
static constexpr size_t OFF_XB   = 0;          // 12,582,912  (also attn out)
static constexpr size_t OFF_WQKV = 12582912;   // 14,155,776
static constexpr size_t OFF_WOUT = 26738688;   //  4,718,592
static constexpr size_t OFF_QKV  = 31457280;   // 37,748,736
static constexpr size_t OFF_Q    = 69206016;   // 12,582,912
static constexpr size_t OFF_K    = 81788928;   // 12,582,912
static constexpr size_t OFF_VT   = 94371840;   // 12,582,912  -> end 106,954,752

extern "C" void kernel_launch(void* const* d_in, const int* in_sizes, int n_in,
                              void* d_out, int out_size, void* d_ws,
                              size_t ws_size, hipStream_t stream) {
  const float* x      = (const float*)d_in[0];
  const float* coords = (const float*)d_in[1];
  const int*   ttype  = (const int*)d_in[2];
  const float* wqkv   = (const float*)d_in[3];
  const float* wout   = (const float*)d_in[4];
  const float* qs     = (const float*)d_in[5];
  const float* ks     = (const float*)d_in[6];

  char* ws = (char*)d_ws;
  __bf16* xb    = (__bf16*)(ws + OFF_XB);
  __bf16* wqkvb = (__bf16*)(ws + OFF_WQKV);
  __bf16* woutb = (__bf16*)(ws + OFF_WOUT);
  __bf16* qkvb  = (__bf16*)(ws + OFF_QKV);
  __bf16* qb    = (__bf16*)(ws + OFF_Q);
  __bf16* kb    = (__bf16*)(ws + OFF_K);
  __bf16* vtb   = (__bf16*)(ws + OFF_VT);
  __bf16* attnb = (__bf16*)(ws + OFF_XB);   // alias

  // 1. fp32 -> bf16 conversions
  {
    const int n4x = NM * NC / 4;            // 1,572,864
    const int n4w = NQKV * NC / 4;          // 1,769,472
    const int n4o = NC * NC / 4;            //   589,824
    cvt_f32_bf16<<<(n4x + 255) / 256, 256, 0, stream>>>(
        (const float4*)x, (bf16x4*)xb, n4x);
    cvt_f32_bf16<<<(n4w + 255) / 256, 256, 0, stream>>>(
        (const float4*)wqkv, (bf16x4*)wqkvb, n4w);
    cvt_f32_bf16<<<(n4o + 255) / 256, 256, 0, stream>>>(
        (const float4*)wout, (bf16x4*)woutb, n4o);
  }
  // 2. qkv = x @ W_qkv^T  (bf16 out)
  gemm_bt<<<dim3(NQKV / 128, NM / 128), 256, 0, stream>>>(
      xb, wqkvb, nullptr, qkvb, NM, NQKV, NC);
  // 3. qk-norm + rope + v-transpose
  normrope_kernel<<<(NB * NT * NH) / 4, 256, 0, stream>>>(
      qkvb, coords, ttype, qs, ks, qb, kb, vtb);
  // 4. causal attention (LDS-staged K/V, mirrored q-pairs)
  attn_fwd2<<<dim3(8, NB * NH), 512, 0, stream>>>(qb, kb, vtb, attnb);
  // 5. out = attn @ W_out^T (fp32 out)
  gemm_bt<<<dim3(NC / 128, NM / 128), 256, 0, stream>>>(
      attnb, woutb, (float*)d_out, nullptr, NM, NC, NC);
}

// Round 2
// 344.664 us; speedup vs baseline: 1.0273x; 1.0273x over previous
//
#include <hip/hip_runtime.h>
#include <stdint.h>
#include <stddef.h>

// ---------------------------------------------------------------------------
// CausalSelfAttention forward, MI355X/gfx950.
// Pipeline: cvt(fp32->bf16) -> GEMM1(qkv, 256^2 8-phase) -> norm+rope ->
//           attn_fwd2 (flash, fixed-max softmax, LDS-staged K/V) ->
//           GEMM2(out proj, fp32, 128^2 2-phase)
// R6 (this round): GEMM1 ported to the 256^2 8-phase schedule (T3+T4+T2+T5).
//     R5 counters: GEMM1 = 126.7us @ 458 TF, MfmaUtil 19%, HBM 16%,
//     bank-conflict rate == m97's -> structure-bound (2-barrier stage drain).
//     New kernel: BM=BN=256 BK=64, 8 waves (2Mx4N), 128KB LDS, 1 half-tile
//     staged/phase via global_load_lds, vmcnt(6) only at ph0/ph4, 2 barriers
//     per phase, slot-XOR swizzle (slot ^= row&7) pre-applied on the global
//     source (linear LDS dest) and on ds_read (same involution, rule #21).
//     Region schedule verified: stage >= 1 barrier-pair after last read;
//     reads follow a barrier that follows all waves' covering vmcnt(6).
// ---------------------------------------------------------------------------

typedef __attribute__((ext_vector_type(8))) __bf16 bf16x8;
typedef __attribute__((ext_vector_type(4))) __bf16 bf16x4;
typedef __attribute__((ext_vector_type(4))) float  f32x4;

#define NB 2
#define NT 2048
#define NC 1536
#define NH 16
#define ND 96
#define NQKV 4608          // 3*NC
#define NM 4096            // NB*NT

static __device__ __forceinline__ float fexp2(float x) {
#if __has_builtin(__builtin_amdgcn_exp2f)
  return __builtin_amdgcn_exp2f(x);
#else
  return exp2f(x);
#endif
}

// async global->LDS, 16B per lane; LDS dest = wave-uniform base + lane*16
static __device__ __forceinline__ void g2lds16(const void* g, void* l) {
  __builtin_amdgcn_global_load_lds(
      (const __attribute__((address_space(1))) void*)g,
      (__attribute__((address_space(3))) void*)l, 16, 0, 0);
}

// ---------------------------------------------------------------------------
// fp32 -> bf16 conversion (vectorized 4-wide)
// ---------------------------------------------------------------------------
__global__ __launch_bounds__(256) void cvt_f32_bf16(
    const float4* __restrict__ src, bf16x4* __restrict__ dst, int n4) {
  int i = blockIdx.x * 256 + threadIdx.x;
  if (i < n4) {
    float4 v = src[i];
    bf16x4 o;
    o[0] = (__bf16)v.x; o[1] = (__bf16)v.y;
    o[2] = (__bf16)v.z; o[3] = (__bf16)v.w;
    dst[i] = o;
  }
}

// ---------------------------------------------------------------------------
// GEMM1: 256x256 tile, BK=64, 8-phase schedule (m194-m201 template).
// C[m][n] = sum_k A[m][k]*B[n][k], A:MxK B:NxK bf16, C bf16.
// 8 waves = 2(M) x 4(N); per-wave output 128x64 = 8x4 frags of 16x16.
// LDS 128KB: A0|A1|B0|B1, each 32KB = 256 rows x 64 cols bf16 (128B rows),
// stored as 8 x 16B slots/row with slot' = slot ^ (row&7) (bank swizzle).
// ---------------------------------------------------------------------------
template <int MQ>
static __device__ __forceinline__ void readA8(
    bf16x8 (&aR)[4][2], const char* buf, int aro, int sk0, int sk1) {
#pragma unroll
  for (int i = 0; i < 4; ++i) {
    const char* p = buf + aro + (MQ * 4 + i) * 2048;
    aR[i][0] = *(const bf16x8*)(p + sk0);
    aR[i][1] = *(const bf16x8*)(p + sk1);
  }
}
template <int NQ>
static __device__ __forceinline__ void readB4(
    bf16x8 (&bb)[2][2], const char* buf, int bro, int sk0, int sk1) {
#pragma unroll
  for (int j = 0; j < 2; ++j) {
    const char* p = buf + bro + (NQ * 2 + j) * 2048;
    bb[j][0] = *(const bf16x8*)(p + sk0);
    bb[j][1] = *(const bf16x8*)(p + sk1);
  }
}
template <int MQ, int NQ>
static __device__ __forceinline__ void quad16(
    f32x4 (&acc)[8][4], const bf16x8 (&aR)[4][2], const bf16x8 (&bb)[2][2]) {
  __builtin_amdgcn_s_setprio(1);
#pragma unroll
  for (int i = 0; i < 4; ++i)
#pragma unroll
    for (int j = 0; j < 2; ++j)
#pragma unroll
      for (int ks = 0; ks < 2; ++ks)
        acc[MQ * 4 + i][NQ * 2 + j] = __builtin_amdgcn_mfma_f32_16x16x32_bf16(
            aR[i][ks], bb[j][ks], acc[MQ * 4 + i][NQ * 2 + j], 0, 0, 0);
  __builtin_amdgcn_s_setprio(0);
}

#define BAR1() do { __builtin_amdgcn_s_barrier(); \
                    asm volatile("" ::: "memory"); } while (0)
#define BAR2() do { asm volatile("" ::: "memory"); \
                    __builtin_amdgcn_s_barrier(); } while (0)
#define WAITLGKM() do { asm volatile("s_waitcnt lgkmcnt(0)" ::: "memory"); \
                        __builtin_amdgcn_sched_barrier(0); } while (0)
#define WAITVM6() asm volatile("s_waitcnt vmcnt(6)" ::: "memory")

__global__ __launch_bounds__(512, 2) void gemm1_8ph(
    const __bf16* __restrict__ A, const __bf16* __restrict__ Bw,
    __bf16* __restrict__ C, int M, int N, int K) {
  __shared__ __align__(16) char lds[131072];
  char* const A0 = lds;
  char* const A1 = lds + 32768;
  char* const B0 = lds + 65536;
  char* const B1 = lds + 98304;

  const int tid = threadIdx.x;
  const int l   = tid & 63;
  const int w   = tid >> 6;        // 0..7
  const int wm  = w >> 2;          // 0..1
  const int wn  = w & 3;           // 0..3
  const int lm  = l & 15;
  const int lq  = l >> 4;

  // XCD-aware bijective tile swizzle (grid 18x16 = 288, %8==0)
  const int nnt = N >> 8;                       // 18
  const int nwg = gridDim.x * gridDim.y;
  const int lid = blockIdx.y * gridDim.x + blockIdx.x;
  const int swz = (lid & 7) * (nwg >> 3) + (lid >> 3);
  const int m0  = (swz / nnt) * 256;
  const int n0  = (swz % nnt) * 256;

  // per-thread ds_read byte offsets (within a 32KB tile buffer)
  const int aro = (wm * 128 + lm) * 128;        // A row base (own M-half)
  const int bro = (wn * 64 + lm) * 128;         // B row base (own 64 cols)
  const int sk0 = ((lq) ^ (lm & 7)) * 16;       // k-slice 0 slot (swizzled)
  const int sk1 = ((4 + lq) ^ (lm & 7)) * 16;   // k-slice 1 slot

  // stage one 16KB half-tile (128 rows x 64 cols): 8 waves x 2 x 1KB.
  // LDS is linear; source k-slot pre-permuted by the same involution the
  // reads apply: src_slot = slot' ^ (row&7), row&7 == (l>>3)&7.
  const int ssl = ((l & 7) ^ ((l >> 3) & 7)) * 8;   // src slot, elements
  auto stageHalf = [&](const __bf16* g, int grow0, int k0, char* ldsHalf) {
#pragma unroll
    for (int q2 = 0; q2 < 2; ++q2) {
      const int c   = w * 2 + q2;
      const int row = c * 8 + (l >> 3);
      g2lds16(g + (size_t)(grow0 + row) * K + k0 + ssl, ldsHalf + c * 1024);
    }
  };

  f32x4 acc[8][4] = {};
  bf16x8 aR[4][2], bL[2][2], bH[2][2];

  // prologue: tile0 (A0,B0 both halves) + tile1 B (B1 both halves)
  stageHalf(A,  m0,       0,  A0);
  stageHalf(A,  m0 + 128, 0,  A0 + 16384);
  stageHalf(Bw, n0,       0,  B0);
  stageHalf(Bw, n0 + 128, 0,  B0 + 16384);
  stageHalf(Bw, n0,       64, B1);
  stageHalf(Bw, n0 + 128, 64, B1 + 16384);

  const int NIT = K >> 7;   // 12 iterations x 2 K-tiles
  for (int it = 0; it < NIT; ++it) {
    const int kh  = it * 128 + 64;
    const int knl = it * 128 + 128;  // next-lo (last iter: benign OOB-read
    const int knh = it * 128 + 192;  //  into adjacent workspace, never used)
    // ph0: stage A1h0(kh); force tile0/A0'/B0' landed; MFMA lo (0,0)
    stageHalf(A, m0, kh, A1);
    WAITVM6();
    BAR1();
    readA8<0>(aR, A0, aro, sk0, sk1);
    readB4<0>(bL, B0, bro, sk0, sk1);
    WAITLGKM();
    quad16<0, 0>(acc, aR, bL);
    BAR2();
    // ph1
    stageHalf(A, m0 + 128, kh, A1 + 16384);
    BAR1();
    readB4<1>(bH, B0, bro, sk0, sk1);
    WAITLGKM();
    quad16<0, 1>(acc, aR, bH);
    BAR2();
    // ph2
    stageHalf(Bw, n0, knl, B0);
    BAR1();
    readA8<1>(aR, A0, aro, sk0, sk1);
    WAITLGKM();
    quad16<1, 1>(acc, aR, bH);
    BAR2();
    // ph3
    stageHalf(Bw, n0 + 128, knl, B0 + 16384);
    BAR1();
    quad16<1, 0>(acc, aR, bL);
    BAR2();
    // ph4: hi K-tile
    stageHalf(A, m0, knl, A0);
    WAITVM6();
    BAR1();
    readA8<0>(aR, A1, aro, sk0, sk1);
    readB4<0>(bL, B1, bro, sk0, sk1);
    WAITLGKM();
    quad16<0, 0>(acc, aR, bL);
    BAR2();
    // ph5
    stageHalf(A, m0 + 128, knl, A0 + 16384);
    BAR1();
    readB4<1>(bH, B1, bro, sk0, sk1);
    WAITLGKM();
    quad16<0, 1>(acc, aR, bH);
    BAR2();
    // ph6
    stageHalf(Bw, n0, knh, B1);
    BAR1();
    readA8<1>(aR, A1, aro, sk0, sk1);
    WAITLGKM();
    quad16<1, 1>(acc, aR, bH);
    BAR2();
    // ph7
    stageHalf(Bw, n0 + 128, knh, B1 + 16384);
    BAR1();
    quad16<1, 0>(acc, aR, bL);
    BAR2();
  }

  // epilogue: C/D layout col=lane&15, row=(lane>>4)*4+r (m89/m91 verified)
  const int r0 = lq * 4;
#pragma unroll
  for (int mf = 0; mf < 8; ++mf)
#pragma unroll
    for (int nf = 0; nf < 4; ++nf)
#pragma unroll
      for (int r = 0; r < 4; ++r) {
        const size_t row = (size_t)(m0 + wm * 128 + mf * 16 + r0 + r);
        const size_t col = (size_t)(n0 + wn * 64 + nf * 16 + lm);
        C[row * N + col] = (__bf16)acc[mf][nf][r];
      }
}

// ---------------------------------------------------------------------------
// GEMM (2-phase 128^2, used for GEMM2): C = A * B^T, fp32 out.
// ---------------------------------------------------------------------------
__global__ __launch_bounds__(256) void gemm_bt(
    const __bf16* __restrict__ A, const __bf16* __restrict__ Bw,
    float* __restrict__ Cf, __bf16* __restrict__ Cb, int M, int N, int K) {
  __shared__ __align__(16) __bf16 Al[128 * 32];
  __shared__ __align__(16) __bf16 Bl[128 * 32];
  const int tid = threadIdx.x;
  const int l   = tid & 63;
  const int w   = tid >> 6;

  // T1 swizzle: nwg % 8 == 0 (384) -> bijective.
  const int nwg = gridDim.x * gridDim.y;
  const int lid = blockIdx.y * gridDim.x + blockIdx.x;
  const int cpx = nwg >> 3;
  const int swz = (lid & 7) * cpx + (lid >> 3);
  const int m0  = (swz / gridDim.x) * 128;
  const int n0  = (swz % gridDim.x) * 128;

  const int wm  = (w >> 1) * 64;
  const int wn  = (w & 1) * 64;
  const int lm  = l & 15;
  const int lq  = l >> 4;
  const int srow = l >> 2;          // row within wave chunk
  const int scol = (l & 3) * 8;     // bf16 element offset in row

  f32x4 acc[4][4] = {};

  for (int k0 = 0; k0 < K; k0 += 32) {
#pragma unroll
    for (int rd = 0; rd < 2; ++rd) {
      const int row = rd * 64 + w * 16 + srow;
      const int lof = rd * 4096 + w * 1024;
      g2lds16(A  + (size_t)(m0 + row) * K + k0 + scol, (char*)Al + lof);
      g2lds16(Bw + (size_t)(n0 + row) * K + k0 + scol, (char*)Bl + lof);
    }
    __syncthreads();
    bf16x8 af[4], bfr[4];
#pragma unroll
    for (int mi = 0; mi < 4; ++mi)
      af[mi] = *(const bf16x8*)(Al + (wm + mi * 16 + lm) * 32 + lq * 8);
#pragma unroll
    for (int ni = 0; ni < 4; ++ni)
      bfr[ni] = *(const bf16x8*)(Bl + (wn + ni * 16 + lm) * 32 + lq * 8);
#pragma unroll
    for (int mi = 0; mi < 4; ++mi)
#pragma unroll
      for (int ni = 0; ni < 4; ++ni)
        acc[mi][ni] = __builtin_amdgcn_mfma_f32_16x16x32_bf16(
            af[mi], bfr[ni], acc[mi][ni], 0, 0, 0);
    __syncthreads();
  }

  const int r0 = lq * 4;
#pragma unroll
  for (int mi = 0; mi < 4; ++mi)
#pragma unroll
    for (int ni = 0; ni < 4; ++ni)
#pragma unroll
      for (int r = 0; r < 4; ++r) {
        const size_t row = (size_t)(m0 + wm + mi * 16 + r0 + r);
        const size_t col = (size_t)(n0 + wn + ni * 16 + lm);
        if (Cf) Cf[row * N + col] = acc[mi][ni][r];
        else    Cb[row * N + col] = (__bf16)acc[mi][ni][r];
      }
}

// ---------------------------------------------------------------------------
// qk RMS-norm + 3D RoPE + layout transform.
// ---------------------------------------------------------------------------
static __device__ __forceinline__ float rope_one(float v, float p, int d,
                                                 const float* c3) {
  const int a  = d >> 5;        // which of 3 coord axes (d3=32)
  const int j  = d & 31;
  const int jj = j & 15;        // half=16
  const float invf = fexp2((float)jj * -0.8304820237218406f);
  const float ang  = c3[a] * invf;
  float sn, cs;
  __sincosf(ang, &sn, &cs);
  return (j < 16) ? (v * cs - p * sn) : (v * cs + p * sn);
}

__global__ __launch_bounds__(256) void normrope_kernel(
    const __bf16* __restrict__ qkv, const float* __restrict__ coords,
    const int* __restrict__ ttype, const float* __restrict__ qsc,
    const float* __restrict__ ksc, __bf16* __restrict__ qo,
    __bf16* __restrict__ ko, __bf16* __restrict__ vo) {
  const int l   = threadIdx.x & 63;
  const int w   = threadIdx.x >> 6;
  const int rid = blockIdx.x * 4 + w;       // (b*T+t)*H + h
  const int h   = rid & (NH - 1);
  const int bt  = rid >> 4;
  const int t   = bt & (NT - 1);
  const int b   = bt >> 11;                 // T = 2048
  const __bf16* base = qkv + (size_t)bt * NQKV + h * ND;
  const float*  c3   = coords + (size_t)bt * 3;
  const bool rope    = ttype[bt] > 0;
  const size_t bh    = (size_t)(b * NH + h);

  // ---- q ----
  {
    float x0 = (float)base[l];
    float x1 = (l < 32) ? (float)base[64 + l] : 0.f;
    float ss = x0 * x0 + x1 * x1;
#pragma unroll
    for (int off = 1; off < 64; off <<= 1) ss += __shfl_xor(ss, off, 64);
    const float rn = rsqrtf(ss * (1.f / 96.f) + 1e-6f);
    x0 *= rn * qsc[l];
    if (l < 32) x1 *= rn * qsc[64 + l];
    const float p0 = __shfl_xor(x0, 16, 64);
    const float p1 = __shfl_xor(x1, 16, 64);
    if (rope) {
      x0 = rope_one(x0, p0, l, c3);
      if (l < 32) x1 = rope_one(x1, p1, 64 + l, c3);
    }
    __bf16* dst = qo + (bh * NT + t) * ND;
    dst[l] = (__bf16)x0;
    if (l < 32) dst[64 + l] = (__bf16)x1;
  }
  // ---- k ----
  {
    float x0 = (float)base[NC + l];
    float x1 = (l < 32) ? (float)base[NC + 64 + l] : 0.f;
    float ss = x0 * x0 + x1 * x1;
#pragma unroll
    for (int off = 1; off < 64; off <<= 1) ss += __shfl_xor(ss, off, 64);
    const float rn = rsqrtf(ss * (1.f / 96.f) + 1e-6f);
    x0 *= rn * ksc[l];
    if (l < 32) x1 *= rn * ksc[64 + l];
    const float p0 = __shfl_xor(x0, 16, 64);
    const float p1 = __shfl_xor(x1, 16, 64);
    if (rope) {
      x0 = rope_one(x0, p0, l, c3);
      if (l < 32) x1 = rope_one(x1, p1, 64 + l, c3);
    }
    __bf16* dst = ko + (bh * NT + t) * ND;
    dst[l] = (__bf16)x0;
    if (l < 32) dst[64 + l] = (__bf16)x1;
  }
  // ---- v (transpose only) ----
  {
    vo[(bh * ND + l) * NT + t] = base[2 * NC + l];
    if (l < 32) vo[(bh * ND + 64 + l) * NT + t] = base[2 * NC + 64 + l];
  }
}

// ---------------------------------------------------------------------------
// Flash attention with LDS-staged K/V, fixed-max softmax. (unchanged R4)
// ---------------------------------------------------------------------------
static __device__ __forceinline__ void attn_tile(
    const bf16x8 (&aq)[3], const bf16x8 (&bk)[2][3], int q0r, int n0,
    int lm, int lq, f32x4& lsum, __bf16* pbase /* 16 rows x 40 */) {
  f32x4 s[2];
#pragma unroll
  for (int nt = 0; nt < 2; ++nt) {
    f32x4 a = {};
#pragma unroll
    for (int c = 0; c < 3; ++c)
      a = __builtin_amdgcn_mfma_f32_16x16x32_bf16(aq[c], bk[nt][c], a, 0, 0, 0);
    s[nt] = a;
  }
  if (n0 + 31 > q0r) {   // diagonal-straddling tile: causal mask
#pragma unroll
    for (int nt = 0; nt < 2; ++nt)
#pragma unroll
      for (int r = 0; r < 4; ++r)
        if (n0 + nt * 16 + lm > q0r + lq * 4 + r) s[nt][r] = -1e30f;
  }
  const float cl = 0.10206207261596575f * 1.4426950408889634f;
#pragma unroll
  for (int nt = 0; nt < 2; ++nt)
#pragma unroll
    for (int r = 0; r < 4; ++r)
      s[nt][r] = fexp2((s[nt][r] - 96.0f) * cl);
#pragma unroll
  for (int r = 0; r < 4; ++r) lsum[r] += s[0][r] + s[1][r];
#pragma unroll
  for (int nt = 0; nt < 2; ++nt)
#pragma unroll
    for (int r = 0; r < 4; ++r)
      pbase[(lq * 4 + r) * 40 + nt * 16 + lm] = (__bf16)s[nt][r];
}

__global__ __launch_bounds__(512) void attn_fwd2(
    const __bf16* __restrict__ q, const __bf16* __restrict__ k,
    const __bf16* __restrict__ vt, __bf16* __restrict__ out) {
  __shared__ __align__(16) char KV[2][12288];        // [buf][K 6KB | V 6KB]
  __shared__ __align__(16) __bf16 plds[8][2][16][40];
  const int tid = threadIdx.x;
  const int l   = tid & 63;
  const int w   = tid >> 6;          // 0..7
  const int bh  = blockIdx.y;
  const int qp  = blockIdx.x;        // 0..7
  const int lm  = l & 15;
  const int lq  = l >> 4;
  const int q0L = qp * 128 + w * 16;
  const int q0H = (15 - qp) * 128 + w * 16;
  const int nktLw = qp * 4 + (w >> 1) + 1;          // causal tiles, frag L
  const int nktHw = (15 - qp) * 4 + (w >> 1) + 1;   // causal tiles, frag H
  const int nkt   = (15 - qp) * 4 + 4;              // block loop bound
  const __bf16* qh = q  + (size_t)bh * NT * ND;
  const __bf16* kh = k  + (size_t)bh * NT * ND;
  const __bf16* vh = vt + (size_t)bh * ND * NT;
  __bf16* pbL = &plds[w][0][0][0];
  __bf16* pbH = &plds[w][1][0][0];

  auto stage = [&](int n0, char* buf) {
    if (w < 6) {
      const int nt = w / 3, c = w - nt * 3;
      g2lds16(kh + (size_t)(n0 + nt * 16 + (l >> 2)) * ND + c * 32 + (l & 3) * 8,
              buf + w * 1024);
    } else {
      const int v = w - 6;
      g2lds16(vh + (size_t)(v * 16 + (l >> 2)) * NT + n0 + (l & 3) * 8,
              buf + 6144 + v * 1024);
    }
    if (w < 4) {
      const int v = 2 + w;
      g2lds16(vh + (size_t)(v * 16 + (l >> 2)) * NT + n0 + (l & 3) * 8,
              buf + 6144 + v * 1024);
    }
  };

  bf16x8 aqL[3], aqH[3];
#pragma unroll
  for (int c = 0; c < 3; ++c) {
    aqL[c] = *(const bf16x8*)(qh + (size_t)(q0L + lm) * ND + c * 32 + lq * 8);
    aqH[c] = *(const bf16x8*)(qh + (size_t)(q0H + lm) * ND + c * 32 + lq * 8);
  }

  f32x4 oL[6] = {}, oH[6] = {};
  f32x4 lsL = {}, lsH = {};
  const int ji = (lm * 4 + lq) * 16;   // this lane's chunk byte offset

  stage(0, KV[0]);
  for (int kt = 0; kt < nkt; ++kt) {
    __syncthreads();                   // drains stage(kt); all waves done kt-1
    if (kt + 1 < nkt) stage((kt + 1) * 32, KV[(kt + 1) & 1]);
    const char* Kc = KV[kt & 1];
    const char* Vc = KV[kt & 1] + 6144;
    const int n0 = kt * 32;
    bf16x8 bk[2][3];
#pragma unroll
    for (int nt = 0; nt < 2; ++nt)
#pragma unroll
      for (int c = 0; c < 3; ++c)
        bk[nt][c] = *(const bf16x8*)(Kc + (nt * 3 + c) * 1024 + ji);
    const bool doL = kt < nktLw;       // wave-uniform
    const bool doH = kt < nktHw;
    if (doL) attn_tile(aqL, bk, q0L, n0, lm, lq, lsL, pbL);
    if (doH) attn_tile(aqH, bk, q0H, n0, lm, lq, lsH, pbH);
    bf16x8 apL = {}, apH = {};
    if (doL) apL = *(const bf16x8*)(pbL + lm * 40 + lq * 8);
    if (doH) apH = *(const bf16x8*)(pbH + lm * 40 + lq * 8);
#pragma unroll
    for (int dt = 0; dt < 6; ++dt) {
      bf16x8 bv = *(const bf16x8*)(Vc + dt * 1024 + ji);
      if (doL) oL[dt] = __builtin_amdgcn_mfma_f32_16x16x32_bf16(apL, bv, oL[dt], 0, 0, 0);
      if (doH) oH[dt] = __builtin_amdgcn_mfma_f32_16x16x32_bf16(apH, bv, oH[dt], 0, 0, 0);
    }
  }

  // epilogue: out[(b*T+t), h*96+d] for both frags
  const int b = bh >> 4, h = bh & 15;
#pragma unroll
  for (int f = 0; f < 2; ++f) {
    const f32x4* o = f ? oH : oL;
    const f32x4& ls = f ? lsH : lsL;
    const int q0 = f ? q0H : q0L;
    float rl[4];
#pragma unroll
    for (int r = 0; r < 4; ++r) {
      float v = ls[r];
#pragma unroll
      for (int off = 1; off < 16; off <<= 1) v += __shfl_xor(v, off, 64);
      rl[r] = 1.f / v;
    }
#pragma unroll
    for (int dt = 0; dt < 6; ++dt)
#pragma unroll
      for (int r = 0; r < 4; ++r) {
        const int t = q0 + lq * 4 + r;
        out[((size_t)(b * NT + t)) * NC + h * ND + dt * 16 + lm] =
            (__bf16)(o[dt][r] * rl[r]);
      }
  }
}

// ---------------------------------------------------------------------------
// workspace layout (bytes); attn-out aliases xb (dead after GEMM1)
// ---------------------------------------------------------------------------
static constexpr size_t OFF_XB   = 0;          // 12,582,912  (also attn out)
static constexpr size_t OFF_WQKV = 12582912;   // 14,155,776
static constexpr size_t OFF_WOUT = 26738688;   //  4,718,592
static constexpr size_t OFF_QKV  = 31457280;   // 37,748,736
static constexpr size_t OFF_Q    = 69206016;   // 12,582,912
static constexpr size_t OFF_K    = 81788928;   // 12,582,912
static constexpr size_t OFF_VT   = 94371840;   // 12,582,912  -> end 106,954,752

extern "C" void kernel_launch(void* const* d_in, const int* in_sizes, int n_in,
                              void* d_out, int out_size, void* d_ws,
                              size_t ws_size, hipStream_t stream) {
  const float* x      = (const float*)d_in[0];
  const float* coords = (const float*)d_in[1];
  const int*   ttype  = (const int*)d_in[2];
  const float* wqkv   = (const float*)d_in[3];
  const float* wout   = (const float*)d_in[4];
  const float* qs     = (const float*)d_in[5];
  const float* ks     = (const float*)d_in[6];

  char* ws = (char*)d_ws;
  __bf16* xb    = (__bf16*)(ws + OFF_XB);
  __bf16* wqkvb = (__bf16*)(ws + OFF_WQKV);
  __bf16* woutb = (__bf16*)(ws + OFF_WOUT);
  __bf16* qkvb  = (__bf16*)(ws + OFF_QKV);
  __bf16* qb    = (__bf16*)(ws + OFF_Q);
  __bf16* kb    = (__bf16*)(ws + OFF_K);
  __bf16* vtb   = (__bf16*)(ws + OFF_VT);
  __bf16* attnb = (__bf16*)(ws + OFF_XB);   // alias

  // 1. fp32 -> bf16 conversions
  {
    const int n4x = NM * NC / 4;            // 1,572,864
    const int n4w = NQKV * NC / 4;          // 1,769,472
    const int n4o = NC * NC / 4;            //   589,824
    cvt_f32_bf16<<<(n4x + 255) / 256, 256, 0, stream>>>(
        (const float4*)x, (bf16x4*)xb, n4x);
    cvt_f32_bf16<<<(n4w + 255) / 256, 256, 0, stream>>>(
        (const float4*)wqkv, (bf16x4*)wqkvb, n4w);
    cvt_f32_bf16<<<(n4o + 255) / 256, 256, 0, stream>>>(
        (const float4*)wout, (bf16x4*)woutb, n4o);
  }
  // 2. qkv = x @ W_qkv^T  (bf16 out, 256^2 8-phase)
  gemm1_8ph<<<dim3(NQKV / 256, NM / 256), 512, 0, stream>>>(
      xb, wqkvb, qkvb, NM, NQKV, NC);
  // 3. qk-norm + rope + v-transpose
  normrope_kernel<<<(NB * NT * NH) / 4, 256, 0, stream>>>(
      qkvb, coords, ttype, qs, ks, qb, kb, vtb);
  // 4. causal attention (LDS-staged K/V, mirrored q-pairs)
  attn_fwd2<<<dim3(8, NB * NH), 512, 0, stream>>>(qb, kb, vtb, attnb);
  // 5. out = attn @ W_out^T (fp32 out)
  gemm_bt<<<dim3(NC / 128, NM / 128), 256, 0, stream>>>(
      attnb, woutb, (float*)d_out, nullptr, NM, NC, NC);
}

// Round 3
// 332.399 us; speedup vs baseline: 1.0652x; 1.0369x over previous
//
#include <hip/hip_runtime.h>
#include <stdint.h>
#include <stddef.h>

// ---------------------------------------------------------------------------
// CausalSelfAttention forward, MI355X/gfx950.
// Pipeline: cvt(fp32->bf16) -> GEMM1(qkv, 256x288 8-phase) -> norm+rope ->
//           attn_fwd2 (flash, fixed-max softmax, LDS-staged K/V) ->
//           GEMM2(out proj, fp32, 128^2 2-phase)
// R7 (this round): GEMM1 tile 256x256 -> 256x288. R6 counters: 88us,
//     MfmaUtil 26%, conflicts 0; deficit = grid 288 @ 1 block/CU -> 2
//     dispatch rounds (slot eff 56%). 4608 = 16*288 -> grid 16x16 = 256
//     blocks = exactly 1/CU, ZERO tail. Waves 4Mx2N, per-wave 64x144
//     (acc[4][9]). B-half = 144 rows = 18 wave-loads (waves 0-1 take one
//     extra granule); per-wave FIFO vmcnt re-derived for both wave classes:
//     vmcnt(6) exact for 2-load waves, safe (<=7) for 3-load waves, at both
//     wait points, prologue through steady state. Buffer anti-deps hold:
//     A0 read ph0-1/staged ph2-3; B0 read ph0,ph2/staged ph4-5; A1 read
//     ph4-5/staged ph6-7; B1 read ph4,ph6/staged next ph0-1 (>=1 barrier).
// ---------------------------------------------------------------------------

typedef __attribute__((ext_vector_type(8))) __bf16 bf16x8;
typedef __attribute__((ext_vector_type(4))) __bf16 bf16x4;
typedef __attribute__((ext_vector_type(4))) float  f32x4;

#define NB 2
#define NT 2048
#define NC 1536
#define NH 16
#define ND 96
#define NQKV 4608          // 3*NC
#define NM 4096            // NB*NT

static __device__ __forceinline__ float fexp2(float x) {
#if __has_builtin(__builtin_amdgcn_exp2f)
  return __builtin_amdgcn_exp2f(x);
#else
  return exp2f(x);
#endif
}

// async global->LDS, 16B per lane; LDS dest = wave-uniform base + lane*16
static __device__ __forceinline__ void g2lds16(const void* g, void* l) {
  __builtin_amdgcn_global_load_lds(
      (const __attribute__((address_space(1))) void*)g,
      (__attribute__((address_space(3))) void*)l, 16, 0, 0);
}

// ---------------------------------------------------------------------------
// fp32 -> bf16 conversion (vectorized 4-wide)
// ---------------------------------------------------------------------------
__global__ __launch_bounds__(256) void cvt_f32_bf16(
    const float4* __restrict__ src, bf16x4* __restrict__ dst, int n4) {
  int i = blockIdx.x * 256 + threadIdx.x;
  if (i < n4) {
    float4 v = src[i];
    bf16x4 o;
    o[0] = (__bf16)v.x; o[1] = (__bf16)v.y;
    o[2] = (__bf16)v.z; o[3] = (__bf16)v.w;
    dst[i] = o;
  }
}

// ---------------------------------------------------------------------------
// GEMM1: 256x288 tile, BK=64, 8-phase schedule. C[m][n]=sum_k A[m][k]B[n][k].
// 8 waves = 4(M) x 2(N); per-wave output 64x144 = 4x9 frags of 16x16.
// LDS 136KB: A0|A1 (32KB each, 256r x 64c) | B0|B1 (36KB each, 288r x 64c),
// 128B rows as 8 x 16B slots with slot' = slot ^ (row&7) (bank swizzle,
// pre-applied on the global source; LDS linear; same XOR on ds_read).
// ---------------------------------------------------------------------------
template <int MH>
static __device__ __forceinline__ void readA2(
    bf16x8 (&aR)[2][2], const char* buf, int aro, int sk0, int sk1) {
#pragma unroll
  for (int i = 0; i < 2; ++i) {
    const char* p = buf + aro + (MH * 2 + i) * 2048;
    aR[i][0] = *(const bf16x8*)(p + sk0);
    aR[i][1] = *(const bf16x8*)(p + sk1);
  }
}
template <int NF0, int NN>
static __device__ __forceinline__ void readBN(
    bf16x8 (&bb)[NN][2], const char* buf, int bro, int sk0, int sk1) {
#pragma unroll
  for (int j = 0; j < NN; ++j) {
    const char* p = buf + bro + (NF0 + j) * 2048;
    bb[j][0] = *(const bf16x8*)(p + sk0);
    bb[j][1] = *(const bf16x8*)(p + sk1);
  }
}
template <int MH, int NF0, int NN>
static __device__ __forceinline__ void quadN(
    f32x4 (&acc)[4][9], const bf16x8 (&aR)[2][2], const bf16x8 (&bb)[NN][2]) {
  __builtin_amdgcn_s_setprio(1);
#pragma unroll
  for (int i = 0; i < 2; ++i)
#pragma unroll
    for (int j = 0; j < NN; ++j)
#pragma unroll
      for (int ks = 0; ks < 2; ++ks)
        acc[MH * 2 + i][NF0 + j] = __builtin_amdgcn_mfma_f32_16x16x32_bf16(
            aR[i][ks], bb[j][ks], acc[MH * 2 + i][NF0 + j], 0, 0, 0);
  __builtin_amdgcn_s_setprio(0);
}

#define BAR1() do { __builtin_amdgcn_s_barrier(); \
                    asm volatile("" ::: "memory"); } while (0)
#define BAR2() do { asm volatile("" ::: "memory"); \
                    __builtin_amdgcn_s_barrier(); } while (0)
#define WAITLGKM() do { asm volatile("s_waitcnt lgkmcnt(0)" ::: "memory"); \
                        __builtin_amdgcn_sched_barrier(0); } while (0)
#define WAITVM6() asm volatile("s_waitcnt vmcnt(6)" ::: "memory")

__global__ __launch_bounds__(512, 2) void gemm1_8ph(
    const __bf16* __restrict__ A, const __bf16* __restrict__ Bw,
    __bf16* __restrict__ C, int M, int N, int K) {
  __shared__ __align__(16) char lds[139264];
  char* const A0 = lds;                 // 32KB
  char* const A1 = lds + 32768;         // 32KB
  char* const B0 = lds + 65536;         // 36KB
  char* const B1 = lds + 102400;        // 36KB

  const int tid = threadIdx.x;
  const int l   = tid & 63;
  const int w   = tid >> 6;        // 0..7
  const int wm  = w >> 1;          // 0..3 (M quarter, 64 rows)
  const int wn  = w & 1;           // 0..1 (N half, 144 cols)
  const int lm  = l & 15;
  const int lq  = l >> 4;

  // XCD-aware bijective tile swizzle (grid 16x16 = 256, %8==0)
  const int nnt = 16;                           // N tiles (4608/288)
  const int nwg = gridDim.x * gridDim.y;        // 256
  const int lid = blockIdx.y * gridDim.x + blockIdx.x;
  const int swz = (lid & 7) * (nwg >> 3) + (lid >> 3);
  const int m0  = (swz / nnt) * 256;
  const int n0  = (swz % nnt) * 288;

  // per-thread ds_read byte offsets (row = 128B = 8 x 16B slots)
  const int aro = (wm * 64 + lm) * 128;         // A row base (own M quarter)
  const int bro = (wn * 144 + lm) * 128;        // B row base (own N half)
  const int sk0 = ((lq) ^ (lm & 7)) * 16;       // k-slice 0 slot (swizzled)
  const int sk1 = ((4 + lq) ^ (lm & 7)) * 16;   // k-slice 1 slot

  // stage: LDS linear, source k-slot pre-permuted by read involution.
  // A half = 128 rows = 16 granules of 8 rows (1KB) -> 2 loads/wave.
  // B half = 144 rows = 18 granules -> waves 0-1 take a 3rd granule.
  const int ssl = ((l & 7) ^ ((l >> 3) & 7)) * 8;   // src slot, elements
  auto stageA = [&](int grow0, int k0, char* dst) {
#pragma unroll
    for (int q2 = 0; q2 < 2; ++q2) {
      const int c   = w * 2 + q2;
      const int row = c * 8 + (l >> 3);
      g2lds16(A + (size_t)(grow0 + row) * K + k0 + ssl, dst + c * 1024);
    }
  };
  auto stageB = [&](int grow0, int k0, char* dst) {
#pragma unroll
    for (int q2 = 0; q2 < 2; ++q2) {
      const int c   = w * 2 + q2;
      const int row = c * 8 + (l >> 3);
      g2lds16(Bw + (size_t)(grow0 + row) * K + k0 + ssl, dst + c * 1024);
    }
    if (w < 2) {
      const int c   = 16 + w;
      const int row = c * 8 + (l >> 3);
      g2lds16(Bw + (size_t)(grow0 + row) * K + k0 + ssl, dst + c * 1024);
    }
  };

  f32x4 acc[4][9] = {};
  bf16x8 aL[2][2], aH[2][2], b5[5][2], b4[4][2];

  // prologue: tile0 A0/B0 + hi-tile A1 (B1 staged in ph0-1 of iter 0)
  stageA(m0,       0,  A0);
  stageA(m0 + 128, 0,  A0 + 16384);
  stageB(n0,       0,  B0);
  stageB(n0 + 144, 0,  B0 + 18432);
  stageA(m0,       64, A1);
  stageA(m0 + 128, 64, A1 + 16384);

  const int NIT = K >> 7;   // 12 iterations x 2 K-tiles
  for (int it = 0; it < NIT; ++it) {
    const int kh  = it * 128 + 64;
    const int knl = it * 128 + 128;  // last iter: benign OOB-read into
    const int knh = it * 128 + 192;  //  adjacent workspace, never consumed
    // ph0: stage B1h0(kh); wait tile0 (A0+B0) landed; Q(Mlo,Nlo)
    stageB(n0, kh, B1);
    WAITVM6();
    BAR1();
    readA2<0>(aL, A0, aro, sk0, sk1);
    readBN<0, 5>(b5, B0, bro, sk0, sk1);
    WAITLGKM();
    quadN<0, 0, 5>(acc, aL, b5);
    BAR2();
    // ph1: Q(Mhi,Nlo)  (aL held for ph3)
    stageB(n0 + 144, kh, B1 + 18432);
    BAR1();
    readA2<1>(aH, A0, aro, sk0, sk1);
    WAITLGKM();
    quadN<1, 0, 5>(acc, aH, b5);
    BAR2();
    // ph2: stage A0'<-knl (A0 reads done ph1); Q(Mhi,Nhi)
    stageA(m0, knl, A0);
    BAR1();
    readBN<5, 4>(b4, B0, bro, sk0, sk1);
    WAITLGKM();
    quadN<1, 5, 4>(acc, aH, b4);
    BAR2();
    // ph3: Q(Mlo,Nhi)  (regs only)
    stageA(m0 + 128, knl, A0 + 16384);
    BAR1();
    quadN<0, 5, 4>(acc, aL, b4);
    BAR2();
    // ph4: hi K-tile (A1/B1); stage B0'<-knl (B0 reads done ph2)
    stageB(n0, knl, B0);
    WAITVM6();
    BAR1();
    readA2<0>(aL, A1, aro, sk0, sk1);
    readBN<0, 5>(b5, B1, bro, sk0, sk1);
    WAITLGKM();
    quadN<0, 0, 5>(acc, aL, b5);
    BAR2();
    // ph5
    stageB(n0 + 144, knl, B0 + 18432);
    BAR1();
    readA2<1>(aH, A1, aro, sk0, sk1);
    WAITLGKM();
    quadN<1, 0, 5>(acc, aH, b5);
    BAR2();
    // ph6: stage A1'<-knh (A1 reads done ph5)
    stageA(m0, knh, A1);
    BAR1();
    readBN<5, 4>(b4, B1, bro, sk0, sk1);
    WAITLGKM();
    quadN<1, 5, 4>(acc, aH, b4);
    BAR2();
    // ph7
    stageA(m0 + 128, knh, A1 + 16384);
    BAR1();
    quadN<0, 5, 4>(acc, aL, b4);
    BAR2();
  }

  // epilogue: C/D layout col=lane&15, row=(lane>>4)*4+r (m89/m91 verified)
  const int r0 = lq * 4;
#pragma unroll
  for (int mf = 0; mf < 4; ++mf)
#pragma unroll
    for (int nf = 0; nf < 9; ++nf)
#pragma unroll
      for (int r = 0; r < 4; ++r) {
        const size_t row = (size_t)(m0 + wm * 64 + mf * 16 + r0 + r);
        const size_t col = (size_t)(n0 + wn * 144 + nf * 16 + lm);
        C[row * N + col] = (__bf16)acc[mf][nf][r];
      }
}

// ---------------------------------------------------------------------------
// GEMM (2-phase 128^2, used for GEMM2): C = A * B^T, fp32 out.
// ---------------------------------------------------------------------------
__global__ __launch_bounds__(256) void gemm_bt(
    const __bf16* __restrict__ A, const __bf16* __restrict__ Bw,
    float* __restrict__ Cf, __bf16* __restrict__ Cb, int M, int N, int K) {
  __shared__ __align__(16) __bf16 Al[128 * 32];
  __shared__ __align__(16) __bf16 Bl[128 * 32];
  const int tid = threadIdx.x;
  const int l   = tid & 63;
  const int w   = tid >> 6;

  // T1 swizzle: nwg % 8 == 0 (384) -> bijective.
  const int nwg = gridDim.x * gridDim.y;
  const int lid = blockIdx.y * gridDim.x + blockIdx.x;
  const int cpx = nwg >> 3;
  const int swz = (lid & 7) * cpx + (lid >> 3);
  const int m0  = (swz / gridDim.x) * 128;
  const int n0  = (swz % gridDim.x) * 128;

  const int wm  = (w >> 1) * 64;
  const int wn  = (w & 1) * 64;
  const int lm  = l & 15;
  const int lq  = l >> 4;
  const int srow = l >> 2;          // row within wave chunk
  const int scol = (l & 3) * 8;     // bf16 element offset in row

  f32x4 acc[4][4] = {};

  for (int k0 = 0; k0 < K; k0 += 32) {
#pragma unroll
    for (int rd = 0; rd < 2; ++rd) {
      const int row = rd * 64 + w * 16 + srow;
      const int lof = rd * 4096 + w * 1024;
      g2lds16(A  + (size_t)(m0 + row) * K + k0 + scol, (char*)Al + lof);
      g2lds16(Bw + (size_t)(n0 + row) * K + k0 + scol, (char*)Bl + lof);
    }
    __syncthreads();
    bf16x8 af[4], bfr[4];
#pragma unroll
    for (int mi = 0; mi < 4; ++mi)
      af[mi] = *(const bf16x8*)(Al + (wm + mi * 16 + lm) * 32 + lq * 8);
#pragma unroll
    for (int ni = 0; ni < 4; ++ni)
      bfr[ni] = *(const bf16x8*)(Bl + (wn + ni * 16 + lm) * 32 + lq * 8);
#pragma unroll
    for (int mi = 0; mi < 4; ++mi)
#pragma unroll
      for (int ni = 0; ni < 4; ++ni)
        acc[mi][ni] = __builtin_amdgcn_mfma_f32_16x16x32_bf16(
            af[mi], bfr[ni], acc[mi][ni], 0, 0, 0);
    __syncthreads();
  }

  const int r0 = lq * 4;
#pragma unroll
  for (int mi = 0; mi < 4; ++mi)
#pragma unroll
    for (int ni = 0; ni < 4; ++ni)
#pragma unroll
      for (int r = 0; r < 4; ++r) {
        const size_t row = (size_t)(m0 + wm + mi * 16 + r0 + r);
        const size_t col = (size_t)(n0 + wn + ni * 16 + lm);
        if (Cf) Cf[row * N + col] = acc[mi][ni][r];
        else    Cb[row * N + col] = (__bf16)acc[mi][ni][r];
      }
}

// ---------------------------------------------------------------------------
// qk RMS-norm + 3D RoPE + layout transform.
// ---------------------------------------------------------------------------
static __device__ __forceinline__ float rope_one(float v, float p, int d,
                                                 const float* c3) {
  const int a  = d >> 5;        // which of 3 coord axes (d3=32)
  const int j  = d & 31;
  const int jj = j & 15;        // half=16
  const float invf = fexp2((float)jj * -0.8304820237218406f);
  const float ang  = c3[a] * invf;
  float sn, cs;
  __sincosf(ang, &sn, &cs);
  return (j < 16) ? (v * cs - p * sn) : (v * cs + p * sn);
}

__global__ __launch_bounds__(256) void normrope_kernel(
    const __bf16* __restrict__ qkv, const float* __restrict__ coords,
    const int* __restrict__ ttype, const float* __restrict__ qsc,
    const float* __restrict__ ksc, __bf16* __restrict__ qo,
    __bf16* __restrict__ ko, __bf16* __restrict__ vo) {
  const int l   = threadIdx.x & 63;
  const int w   = threadIdx.x >> 6;
  const int rid = blockIdx.x * 4 + w;       // (b*T+t)*H + h
  const int h   = rid & (NH - 1);
  const int bt  = rid >> 4;
  const int t   = bt & (NT - 1);
  const int b   = bt >> 11;                 // T = 2048
  const __bf16* base = qkv + (size_t)bt * NQKV + h * ND;
  const float*  c3   = coords + (size_t)bt * 3;
  const bool rope    = ttype[bt] > 0;
  const size_t bh    = (size_t)(b * NH + h);

  // ---- q ----
  {
    float x0 = (float)base[l];
    float x1 = (l < 32) ? (float)base[64 + l] : 0.f;
    float ss = x0 * x0 + x1 * x1;
#pragma unroll
    for (int off = 1; off < 64; off <<= 1) ss += __shfl_xor(ss, off, 64);
    const float rn = rsqrtf(ss * (1.f / 96.f) + 1e-6f);
    x0 *= rn * qsc[l];
    if (l < 32) x1 *= rn * qsc[64 + l];
    const float p0 = __shfl_xor(x0, 16, 64);
    const float p1 = __shfl_xor(x1, 16, 64);
    if (rope) {
      x0 = rope_one(x0, p0, l, c3);
      if (l < 32) x1 = rope_one(x1, p1, 64 + l, c3);
    }
    __bf16* dst = qo + (bh * NT + t) * ND;
    dst[l] = (__bf16)x0;
    if (l < 32) dst[64 + l] = (__bf16)x1;
  }
  // ---- k ----
  {
    float x0 = (float)base[NC + l];
    float x1 = (l < 32) ? (float)base[NC + 64 + l] : 0.f;
    float ss = x0 * x0 + x1 * x1;
#pragma unroll
    for (int off = 1; off < 64; off <<= 1) ss += __shfl_xor(ss, off, 64);
    const float rn = rsqrtf(ss * (1.f / 96.f) + 1e-6f);
    x0 *= rn * ksc[l];
    if (l < 32) x1 *= rn * ksc[64 + l];
    const float p0 = __shfl_xor(x0, 16, 64);
    const float p1 = __shfl_xor(x1, 16, 64);
    if (rope) {
      x0 = rope_one(x0, p0, l, c3);
      if (l < 32) x1 = rope_one(x1, p1, 64 + l, c3);
    }
    __bf16* dst = ko + (bh * NT + t) * ND;
    dst[l] = (__bf16)x0;
    if (l < 32) dst[64 + l] = (__bf16)x1;
  }
  // ---- v (transpose only) ----
  {
    vo[(bh * ND + l) * NT + t] = base[2 * NC + l];
    if (l < 32) vo[(bh * ND + 64 + l) * NT + t] = base[2 * NC + 64 + l];
  }
}

// ---------------------------------------------------------------------------
// Flash attention with LDS-staged K/V, fixed-max softmax. (unchanged R4)
// ---------------------------------------------------------------------------
static __device__ __forceinline__ void attn_tile(
    const bf16x8 (&aq)[3], const bf16x8 (&bk)[2][3], int q0r, int n0,
    int lm, int lq, f32x4& lsum, __bf16* pbase /* 16 rows x 40 */) {
  f32x4 s[2];
#pragma unroll
  for (int nt = 0; nt < 2; ++nt) {
    f32x4 a = {};
#pragma unroll
    for (int c = 0; c < 3; ++c)
      a = __builtin_amdgcn_mfma_f32_16x16x32_bf16(aq[c], bk[nt][c], a, 0, 0, 0);
    s[nt] = a;
  }
  if (n0 + 31 > q0r) {   // diagonal-straddling tile: causal mask
#pragma unroll
    for (int nt = 0; nt < 2; ++nt)
#pragma unroll
      for (int r = 0; r < 4; ++r)
        if (n0 + nt * 16 + lm > q0r + lq * 4 + r) s[nt][r] = -1e30f;
  }
  const float cl = 0.10206207261596575f * 1.4426950408889634f;
#pragma unroll
  for (int nt = 0; nt < 2; ++nt)
#pragma unroll
    for (int r = 0; r < 4; ++r)
      s[nt][r] = fexp2((s[nt][r] - 96.0f) * cl);
#pragma unroll
  for (int r = 0; r < 4; ++r) lsum[r] += s[0][r] + s[1][r];
#pragma unroll
  for (int nt = 0; nt < 2; ++nt)
#pragma unroll
    for (int r = 0; r < 4; ++r)
      pbase[(lq * 4 + r) * 40 + nt * 16 + lm] = (__bf16)s[nt][r];
}

__global__ __launch_bounds__(512) void attn_fwd2(
    const __bf16* __restrict__ q, const __bf16* __restrict__ k,
    const __bf16* __restrict__ vt, __bf16* __restrict__ out) {
  __shared__ __align__(16) char KV[2][12288];        // [buf][K 6KB | V 6KB]
  __shared__ __align__(16) __bf16 plds[8][2][16][40];
  const int tid = threadIdx.x;
  const int l   = tid & 63;
  const int w   = tid >> 6;          // 0..7
  const int bh  = blockIdx.y;
  const int qp  = blockIdx.x;        // 0..7
  const int lm  = l & 15;
  const int lq  = l >> 4;
  const int q0L = qp * 128 + w * 16;
  const int q0H = (15 - qp) * 128 + w * 16;
  const int nktLw = qp * 4 + (w >> 1) + 1;          // causal tiles, frag L
  const int nktHw = (15 - qp) * 4 + (w >> 1) + 1;   // causal tiles, frag H
  const int nkt   = (15 - qp) * 4 + 4;              // block loop bound
  const __bf16* qh = q  + (size_t)bh * NT * ND;
  const __bf16* kh = k  + (size_t)bh * NT * ND;
  const __bf16* vh = vt + (size_t)bh * ND * NT;
  __bf16* pbL = &plds[w][0][0][0];
  __bf16* pbH = &plds[w][1][0][0];

  auto stage = [&](int n0, char* buf) {
    if (w < 6) {
      const int nt = w / 3, c = w - nt * 3;
      g2lds16(kh + (size_t)(n0 + nt * 16 + (l >> 2)) * ND + c * 32 + (l & 3) * 8,
              buf + w * 1024);
    } else {
      const int v = w - 6;
      g2lds16(vh + (size_t)(v * 16 + (l >> 2)) * NT + n0 + (l & 3) * 8,
              buf + 6144 + v * 1024);
    }
    if (w < 4) {
      const int v = 2 + w;
      g2lds16(vh + (size_t)(v * 16 + (l >> 2)) * NT + n0 + (l & 3) * 8,
              buf + 6144 + v * 1024);
    }
  };

  bf16x8 aqL[3], aqH[3];
#pragma unroll
  for (int c = 0; c < 3; ++c) {
    aqL[c] = *(const bf16x8*)(qh + (size_t)(q0L + lm) * ND + c * 32 + lq * 8);
    aqH[c] = *(const bf16x8*)(qh + (size_t)(q0H + lm) * ND + c * 32 + lq * 8);
  }

  f32x4 oL[6] = {}, oH[6] = {};
  f32x4 lsL = {}, lsH = {};
  const int ji = (lm * 4 + lq) * 16;   // this lane's chunk byte offset

  stage(0, KV[0]);
  for (int kt = 0; kt < nkt; ++kt) {
    __syncthreads();                   // drains stage(kt); all waves done kt-1
    if (kt + 1 < nkt) stage((kt + 1) * 32, KV[(kt + 1) & 1]);
    const char* Kc = KV[kt & 1];
    const char* Vc = KV[kt & 1] + 6144;
    const int n0 = kt * 32;
    bf16x8 bk[2][3];
#pragma unroll
    for (int nt = 0; nt < 2; ++nt)
#pragma unroll
      for (int c = 0; c < 3; ++c)
        bk[nt][c] = *(const bf16x8*)(Kc + (nt * 3 + c) * 1024 + ji);
    const bool doL = kt < nktLw;       // wave-uniform
    const bool doH = kt < nktHw;
    if (doL) attn_tile(aqL, bk, q0L, n0, lm, lq, lsL, pbL);
    if (doH) attn_tile(aqH, bk, q0H, n0, lm, lq, lsH, pbH);
    bf16x8 apL = {}, apH = {};
    if (doL) apL = *(const bf16x8*)(pbL + lm * 40 + lq * 8);
    if (doH) apH = *(const bf16x8*)(pbH + lm * 40 + lq * 8);
#pragma unroll
    for (int dt = 0; dt < 6; ++dt) {
      bf16x8 bv = *(const bf16x8*)(Vc + dt * 1024 + ji);
      if (doL) oL[dt] = __builtin_amdgcn_mfma_f32_16x16x32_bf16(apL, bv, oL[dt], 0, 0, 0);
      if (doH) oH[dt] = __builtin_amdgcn_mfma_f32_16x16x32_bf16(apH, bv, oH[dt], 0, 0, 0);
    }
  }

  // epilogue: out[(b*T+t), h*96+d] for both frags
  const int b = bh >> 4, h = bh & 15;
#pragma unroll
  for (int f = 0; f < 2; ++f) {
    const f32x4* o = f ? oH : oL;
    const f32x4& ls = f ? lsH : lsL;
    const int q0 = f ? q0H : q0L;
    float rl[4];
#pragma unroll
    for (int r = 0; r < 4; ++r) {
      float v = ls[r];
#pragma unroll
      for (int off = 1; off < 16; off <<= 1) v += __shfl_xor(v, off, 64);
      rl[r] = 1.f / v;
    }
#pragma unroll
    for (int dt = 0; dt < 6; ++dt)
#pragma unroll
      for (int r = 0; r < 4; ++r) {
        const int t = q0 + lq * 4 + r;
        out[((size_t)(b * NT + t)) * NC + h * ND + dt * 16 + lm] =
            (__bf16)(o[dt][r] * rl[r]);
      }
  }
}

// ---------------------------------------------------------------------------
// workspace layout (bytes); attn-out aliases xb (dead after GEMM1)
// ---------------------------------------------------------------------------
static constexpr size_t OFF_XB   = 0;          // 12,582,912  (also attn out)
static constexpr size_t OFF_WQKV = 12582912;   // 14,155,776
static constexpr size_t OFF_WOUT = 26738688;   //  4,718,592
static constexpr size_t OFF_QKV  = 31457280;   // 37,748,736
static constexpr size_t OFF_Q    = 69206016;   // 12,582,912
static constexpr size_t OFF_K    = 81788928;   // 12,582,912
static constexpr size_t OFF_VT   = 94371840;   // 12,582,912  -> end 106,954,752

extern "C" void kernel_launch(void* const* d_in, const int* in_sizes, int n_in,
                              void* d_out, int out_size, void* d_ws,
                              size_t ws_size, hipStream_t stream) {
  const float* x      = (const float*)d_in[0];
  const float* coords = (const float*)d_in[1];
  const int*   ttype  = (const int*)d_in[2];
  const float* wqkv   = (const float*)d_in[3];
  const float* wout   = (const float*)d_in[4];
  const float* qs     = (const float*)d_in[5];
  const float* ks     = (const float*)d_in[6];

  char* ws = (char*)d_ws;
  __bf16* xb    = (__bf16*)(ws + OFF_XB);
  __bf16* wqkvb = (__bf16*)(ws + OFF_WQKV);
  __bf16* woutb = (__bf16*)(ws + OFF_WOUT);
  __bf16* qkvb  = (__bf16*)(ws + OFF_QKV);
  __bf16* qb    = (__bf16*)(ws + OFF_Q);
  __bf16* kb    = (__bf16*)(ws + OFF_K);
  __bf16* vtb   = (__bf16*)(ws + OFF_VT);
  __bf16* attnb = (__bf16*)(ws + OFF_XB);   // alias

  // 1. fp32 -> bf16 conversions
  {
    const int n4x = NM * NC / 4;            // 1,572,864
    const int n4w = NQKV * NC / 4;          // 1,769,472
    const int n4o = NC * NC / 4;            //   589,824
    cvt_f32_bf16<<<(n4x + 255) / 256, 256, 0, stream>>>(
        (const float4*)x, (bf16x4*)xb, n4x);
    cvt_f32_bf16<<<(n4w + 255) / 256, 256, 0, stream>>>(
        (const float4*)wqkv, (bf16x4*)wqkvb, n4w);
    cvt_f32_bf16<<<(n4o + 255) / 256, 256, 0, stream>>>(
        (const float4*)wout, (bf16x4*)woutb, n4o);
  }
  // 2. qkv = x @ W_qkv^T  (bf16 out, 256x288 8-phase, grid 16x16=256)
  gemm1_8ph<<<dim3(NQKV / 288, NM / 256), 512, 0, stream>>>(
      xb, wqkvb, qkvb, NM, NQKV, NC);
  // 3. qk-norm + rope + v-transpose
  normrope_kernel<<<(NB * NT * NH) / 4, 256, 0, stream>>>(
      qkvb, coords, ttype, qs, ks, qb, kb, vtb);
  // 4. causal attention (LDS-staged K/V, mirrored q-pairs)
  attn_fwd2<<<dim3(8, NB * NH), 512, 0, stream>>>(qb, kb, vtb, attnb);
  // 5. out = attn @ W_out^T (fp32 out)
  gemm_bt<<<dim3(NC / 128, NM / 128), 256, 0, stream>>>(
      attnb, woutb, (float*)d_out, nullptr, NM, NC, NC);
}

// Round 4
// 304.875 us; speedup vs baseline: 1.1614x; 1.0903x over previous
//
#include <hip/hip_runtime.h>
#include <stdint.h>
#include <stddef.h>

// ---------------------------------------------------------------------------
// CausalSelfAttention forward, MI355X/gfx950.
// Pipeline: cvt(fp32->bf16) -> GEMM1(qkv, 256x288 8-phase) ->
//           normrope(q,k) + transpose_v -> attn_fwd2 -> GEMM2(128x192 8-phase)
// R8 (this round): GEMM1/attn untouched (GEMM1 83.9us, MfmaUtil 26.6%).
//     Attack the unprofiled 248us:
//     (1) V-transpose moved out of normrope into LDS-tiled transpose_v --
//         old path wrote vo with 4KB lane stride (64 sectors/instr, same
//         sector written by blocks on different XCDs -> partial-sector
//         false sharing). New kernel: coalesced reads, LDS tile, 16B
//         vector writes in 512B runs. Ideal ~25MB -> ~5-6us.
//     (2) GEMM2 ported from 2-phase 128^2 (458-TF class) to 8-phase
//         BM=128/BN=192: grid 8x32 = 256 blocks (zero tail), LDS 80KB,
//         UNIFORM staging (A=2, B=3 loads/wave), vmcnt(5) at ph0/ph4 only
//         (FIFO-verified), quadrant rotation w/ verified anti-deps.
// ---------------------------------------------------------------------------

typedef __attribute__((ext_vector_type(8))) __bf16 bf16x8;
typedef __attribute__((ext_vector_type(4))) __bf16 bf16x4;
typedef __attribute__((ext_vector_type(4))) float  f32x4;

#define NB 2
#define NT 2048
#define NC 1536
#define NH 16
#define ND 96
#define NQKV 4608          // 3*NC
#define NM 4096            // NB*NT

static __device__ __forceinline__ float fexp2(float x) {
#if __has_builtin(__builtin_amdgcn_exp2f)
  return __builtin_amdgcn_exp2f(x);
#else
  return exp2f(x);
#endif
}

// async global->LDS, 16B per lane; LDS dest = wave-uniform base + lane*16
static __device__ __forceinline__ void g2lds16(const void* g, void* l) {
  __builtin_amdgcn_global_load_lds(
      (const __attribute__((address_space(1))) void*)g,
      (__attribute__((address_space(3))) void*)l, 16, 0, 0);
}

// ---------------------------------------------------------------------------
// fp32 -> bf16 conversion (vectorized 4-wide)
// ---------------------------------------------------------------------------
__global__ __launch_bounds__(256) void cvt_f32_bf16(
    const float4* __restrict__ src, bf16x4* __restrict__ dst, int n4) {
  int i = blockIdx.x * 256 + threadIdx.x;
  if (i < n4) {
    float4 v = src[i];
    bf16x4 o;
    o[0] = (__bf16)v.x; o[1] = (__bf16)v.y;
    o[2] = (__bf16)v.z; o[3] = (__bf16)v.w;
    dst[i] = o;
  }
}

// ---------------------------------------------------------------------------
// shared 8-phase helpers
// ---------------------------------------------------------------------------
#define BAR1() do { __builtin_amdgcn_s_barrier(); \
                    asm volatile("" ::: "memory"); } while (0)
#define BAR2() do { asm volatile("" ::: "memory"); \
                    __builtin_amdgcn_s_barrier(); } while (0)
#define WAITLGKM() do { asm volatile("s_waitcnt lgkmcnt(0)" ::: "memory"); \
                        __builtin_amdgcn_sched_barrier(0); } while (0)
#define WAITVM6() asm volatile("s_waitcnt vmcnt(6)" ::: "memory")
#define WAITVM5() asm volatile("s_waitcnt vmcnt(5)" ::: "memory")

// ---------------------------------------------------------------------------
// GEMM1: 256x288 tile, BK=64, 8-phase schedule (unchanged from R7).
// ---------------------------------------------------------------------------
template <int MH>
static __device__ __forceinline__ void readA2(
    bf16x8 (&aR)[2][2], const char* buf, int aro, int sk0, int sk1) {
#pragma unroll
  for (int i = 0; i < 2; ++i) {
    const char* p = buf + aro + (MH * 2 + i) * 2048;
    aR[i][0] = *(const bf16x8*)(p + sk0);
    aR[i][1] = *(const bf16x8*)(p + sk1);
  }
}
template <int NF0, int NN>
static __device__ __forceinline__ void readBN(
    bf16x8 (&bb)[NN][2], const char* buf, int bro, int sk0, int sk1) {
#pragma unroll
  for (int j = 0; j < NN; ++j) {
    const char* p = buf + bro + (NF0 + j) * 2048;
    bb[j][0] = *(const bf16x8*)(p + sk0);
    bb[j][1] = *(const bf16x8*)(p + sk1);
  }
}
template <int MH, int NF0, int NN>
static __device__ __forceinline__ void quadN(
    f32x4 (&acc)[4][9], const bf16x8 (&aR)[2][2], const bf16x8 (&bb)[NN][2]) {
  __builtin_amdgcn_s_setprio(1);
#pragma unroll
  for (int i = 0; i < 2; ++i)
#pragma unroll
    for (int j = 0; j < NN; ++j)
#pragma unroll
      for (int ks = 0; ks < 2; ++ks)
        acc[MH * 2 + i][NF0 + j] = __builtin_amdgcn_mfma_f32_16x16x32_bf16(
            aR[i][ks], bb[j][ks], acc[MH * 2 + i][NF0 + j], 0, 0, 0);
  __builtin_amdgcn_s_setprio(0);
}

__global__ __launch_bounds__(512, 2) void gemm1_8ph(
    const __bf16* __restrict__ A, const __bf16* __restrict__ Bw,
    __bf16* __restrict__ C, int M, int N, int K) {
  __shared__ __align__(16) char lds[139264];
  char* const A0 = lds;                 // 32KB
  char* const A1 = lds + 32768;         // 32KB
  char* const B0 = lds + 65536;         // 36KB
  char* const B1 = lds + 102400;        // 36KB

  const int tid = threadIdx.x;
  const int l   = tid & 63;
  const int w   = tid >> 6;        // 0..7
  const int wm  = w >> 1;          // 0..3 (M quarter, 64 rows)
  const int wn  = w & 1;           // 0..1 (N half, 144 cols)
  const int lm  = l & 15;
  const int lq  = l >> 4;

  // XCD-aware bijective tile swizzle (grid 16x16 = 256, %8==0)
  const int nnt = 16;                           // N tiles (4608/288)
  const int nwg = gridDim.x * gridDim.y;        // 256
  const int lid = blockIdx.y * gridDim.x + blockIdx.x;
  const int swz = (lid & 7) * (nwg >> 3) + (lid >> 3);
  const int m0  = (swz / nnt) * 256;
  const int n0  = (swz % nnt) * 288;

  const int aro = (wm * 64 + lm) * 128;         // A row base (own M quarter)
  const int bro = (wn * 144 + lm) * 128;        // B row base (own N half)
  const int sk0 = ((lq) ^ (lm & 7)) * 16;       // k-slice 0 slot (swizzled)
  const int sk1 = ((4 + lq) ^ (lm & 7)) * 16;   // k-slice 1 slot

  const int ssl = ((l & 7) ^ ((l >> 3) & 7)) * 8;   // src slot, elements
  auto stageA = [&](int grow0, int k0, char* dst) {
#pragma unroll
    for (int q2 = 0; q2 < 2; ++q2) {
      const int c   = w * 2 + q2;
      const int row = c * 8 + (l >> 3);
      g2lds16(A + (size_t)(grow0 + row) * K + k0 + ssl, dst + c * 1024);
    }
  };
  auto stageB = [&](int grow0, int k0, char* dst) {
#pragma unroll
    for (int q2 = 0; q2 < 2; ++q2) {
      const int c   = w * 2 + q2;
      const int row = c * 8 + (l >> 3);
      g2lds16(Bw + (size_t)(grow0 + row) * K + k0 + ssl, dst + c * 1024);
    }
    if (w < 2) {
      const int c   = 16 + w;
      const int row = c * 8 + (l >> 3);
      g2lds16(Bw + (size_t)(grow0 + row) * K + k0 + ssl, dst + c * 1024);
    }
  };

  f32x4 acc[4][9] = {};
  bf16x8 aL[2][2], aH[2][2], b5[5][2], b4[4][2];

  stageA(m0,       0,  A0);
  stageA(m0 + 128, 0,  A0 + 16384);
  stageB(n0,       0,  B0);
  stageB(n0 + 144, 0,  B0 + 18432);
  stageA(m0,       64, A1);
  stageA(m0 + 128, 64, A1 + 16384);

  const int NIT = K >> 7;   // 12 iterations x 2 K-tiles
  for (int it = 0; it < NIT; ++it) {
    const int kh  = it * 128 + 64;
    const int knl = it * 128 + 128;  // last iter: benign OOB-read into
    const int knh = it * 128 + 192;  //  adjacent workspace, never consumed
    stageB(n0, kh, B1);
    WAITVM6();
    BAR1();
    readA2<0>(aL, A0, aro, sk0, sk1);
    readBN<0, 5>(b5, B0, bro, sk0, sk1);
    WAITLGKM();
    quadN<0, 0, 5>(acc, aL, b5);
    BAR2();
    stageB(n0 + 144, kh, B1 + 18432);
    BAR1();
    readA2<1>(aH, A0, aro, sk0, sk1);
    WAITLGKM();
    quadN<1, 0, 5>(acc, aH, b5);
    BAR2();
    stageA(m0, knl, A0);
    BAR1();
    readBN<5, 4>(b4, B0, bro, sk0, sk1);
    WAITLGKM();
    quadN<1, 5, 4>(acc, aH, b4);
    BAR2();
    stageA(m0 + 128, knl, A0 + 16384);
    BAR1();
    quadN<0, 5, 4>(acc, aL, b4);
    BAR2();
    stageB(n0, knl, B0);
    WAITVM6();
    BAR1();
    readA2<0>(aL, A1, aro, sk0, sk1);
    readBN<0, 5>(b5, B1, bro, sk0, sk1);
    WAITLGKM();
    quadN<0, 0, 5>(acc, aL, b5);
    BAR2();
    stageB(n0 + 144, knl, B0 + 18432);
    BAR1();
    readA2<1>(aH, A1, aro, sk0, sk1);
    WAITLGKM();
    quadN<1, 0, 5>(acc, aH, b5);
    BAR2();
    stageA(m0, knh, A1);
    BAR1();
    readBN<5, 4>(b4, B1, bro, sk0, sk1);
    WAITLGKM();
    quadN<1, 5, 4>(acc, aH, b4);
    BAR2();
    stageA(m0 + 128, knh, A1 + 16384);
    BAR1();
    quadN<0, 5, 4>(acc, aL, b4);
    BAR2();
  }

  const int r0 = lq * 4;
#pragma unroll
  for (int mf = 0; mf < 4; ++mf)
#pragma unroll
    for (int nf = 0; nf < 9; ++nf)
#pragma unroll
      for (int r = 0; r < 4; ++r) {
        const size_t row = (size_t)(m0 + wm * 64 + mf * 16 + r0 + r);
        const size_t col = (size_t)(n0 + wn * 144 + nf * 16 + lm);
        C[row * N + col] = (__bf16)acc[mf][nf][r];
      }
}

// ---------------------------------------------------------------------------
// GEMM2: 128x192 tile, BK=64, 8-phase, fp32 out. Grid 8x32 = 256 (zero tail).
// 8 waves = 2(M) x 4(N); per-wave 64x48 = 4x3 frags. LDS 80KB:
// A0|A1 (16KB, 128r x 64c) | B0|B1 (24KB, 192r x 64c). Uniform staging:
// A = 16 granules (2/wave), B = 24 granules (3/wave); whole-tile calls.
// vmcnt(5) at ph0/ph4: steady-state FIFO [A_lo(2),B_lo(3),A_hi(2)] (+3 new)
// -> drain 5 = exactly the tile about to be read; newest drained load was
// issued 4 phases earlier. Anti-deps: A0 read ph0-1/staged ph2; B0 read
// ph0,ph2/staged ph4; A1 read ph4-5/staged ph6; B1 read ph4,ph6/staged
// next ph0 (>=1 barrier between last read and restage).
// ---------------------------------------------------------------------------
template <int MH>
static __device__ __forceinline__ void g2readA(
    bf16x8 (&aR)[2][2], const char* buf, int aro, int sk0, int sk1) {
#pragma unroll
  for (int i = 0; i < 2; ++i) {
    const char* p = buf + aro + (MH * 2 + i) * 2048;
    aR[i][0] = *(const bf16x8*)(p + sk0);
    aR[i][1] = *(const bf16x8*)(p + sk1);
  }
}
template <int NF0, int NN>
static __device__ __forceinline__ void g2readB(
    bf16x8 (&bb)[NN][2], const char* buf, int bro, int sk0, int sk1) {
#pragma unroll
  for (int j = 0; j < NN; ++j) {
    const char* p = buf + bro + (NF0 + j) * 2048;
    bb[j][0] = *(const bf16x8*)(p + sk0);
    bb[j][1] = *(const bf16x8*)(p + sk1);
  }
}
template <int MH, int NF0, int NN>
static __device__ __forceinline__ void g2quad(
    f32x4 (&acc)[4][3], const bf16x8 (&aR)[2][2], const bf16x8 (&bb)[NN][2]) {
  __builtin_amdgcn_s_setprio(1);
#pragma unroll
  for (int i = 0; i < 2; ++i)
#pragma unroll
    for (int j = 0; j < NN; ++j)
#pragma unroll
      for (int ks = 0; ks < 2; ++ks)
        acc[MH * 2 + i][NF0 + j] = __builtin_amdgcn_mfma_f32_16x16x32_bf16(
            aR[i][ks], bb[j][ks], acc[MH * 2 + i][NF0 + j], 0, 0, 0);
  __builtin_amdgcn_s_setprio(0);
}

__global__ __launch_bounds__(512, 2) void gemm2_8ph(
    const __bf16* __restrict__ A, const __bf16* __restrict__ Bw,
    float* __restrict__ C, int M, int N, int K) {
  __shared__ __align__(16) char lds[81920];
  char* const A0 = lds;                 // 16KB
  char* const A1 = lds + 16384;         // 16KB
  char* const B0 = lds + 32768;         // 24KB
  char* const B1 = lds + 57344;         // 24KB

  const int tid = threadIdx.x;
  const int l   = tid & 63;
  const int w   = tid >> 6;        // 0..7
  const int wm  = w >> 2;          // 0..1 (M half, 64 rows)
  const int wn  = w & 3;           // 0..3 (N quarter, 48 cols)
  const int lm  = l & 15;
  const int lq  = l >> 4;

  // XCD-aware bijective tile swizzle (grid 8x32 = 256, %8==0)
  const int nwg = gridDim.x * gridDim.y;        // 256
  const int lid = blockIdx.y * gridDim.x + blockIdx.x;
  const int swz = (lid & 7) * (nwg >> 3) + (lid >> 3);
  const int m0  = (swz / 8) * 128;
  const int n0  = (swz % 8) * 192;

  const int aro = (wm * 64 + lm) * 128;         // A row base (own M half)
  const int bro = (wn * 48 + lm) * 128;         // B row base (own N quarter)
  const int sk0 = ((lq) ^ (lm & 7)) * 16;
  const int sk1 = ((4 + lq) ^ (lm & 7)) * 16;

  const int ssl = ((l & 7) ^ ((l >> 3) & 7)) * 8;
  auto stageA = [&](int k0, char* dst) {          // 128 rows = 16 granules
#pragma unroll
    for (int q2 = 0; q2 < 2; ++q2) {
      const int c   = w * 2 + q2;
      const int row = c * 8 + (l >> 3);
      g2lds16(A + (size_t)(m0 + row) * K + k0 + ssl, dst + c * 1024);
    }
  };
  auto stageB = [&](int k0, char* dst) {          // 192 rows = 24 granules
#pragma unroll
    for (int q2 = 0; q2 < 3; ++q2) {
      const int c   = w * 3 + q2;
      const int row = c * 8 + (l >> 3);
      g2lds16(Bw + (size_t)(n0 + row) * K + k0 + ssl, dst + c * 1024);
    }
  };

  f32x4 acc[4][3] = {};
  bf16x8 aL[2][2], aH[2][2], bL[2][2], bH[1][2];

  // prologue: A0/B0 (tile lo) + A1 (tile hi); B1 staged in ph0 of iter 0.
  stageA(0,  A0);
  stageB(0,  B0);
  stageA(64, A1);                       // 7 outstanding/wave

  const int NIT = K >> 7;   // 12 iterations x 2 K-tiles
  for (int it = 0; it < NIT; ++it) {
    const int kh  = it * 128 + 64;
    const int knl = it * 128 + 128;  // last iter: benign OOB-read into
    const int knh = it * 128 + 192;  //  adjacent workspace, never consumed
    // ph0: stage B1<-kh; wait lo tile (A0+B0); Q(Mlo,Nlo01)
    stageB(kh, B1);
    WAITVM5();
    BAR1();
    g2readA<0>(aL, A0, aro, sk0, sk1);
    g2readB<0, 2>(bL, B0, bro, sk0, sk1);
    WAITLGKM();
    g2quad<0, 0, 2>(acc, aL, bL);
    BAR2();
    // ph1: Q(Mhi,Nlo01)
    BAR1();
    g2readA<1>(aH, A0, aro, sk0, sk1);
    WAITLGKM();
    g2quad<1, 0, 2>(acc, aH, bL);
    BAR2();
    // ph2: stage A0<-knl (A0 reads done ph1); Q(Mhi,Nhi2)
    stageA(knl, A0);
    BAR1();
    g2readB<2, 1>(bH, B0, bro, sk0, sk1);
    WAITLGKM();
    g2quad<1, 2, 1>(acc, aH, bH);
    BAR2();
    // ph3: Q(Mlo,Nhi2) (regs only)
    BAR1();
    g2quad<0, 2, 1>(acc, aL, bH);
    BAR2();
    // ph4: hi K-tile; stage B0<-knl (B0 reads done ph2); wait A1+B1
    stageB(knl, B0);
    WAITVM5();
    BAR1();
    g2readA<0>(aL, A1, aro, sk0, sk1);
    g2readB<0, 2>(bL, B1, bro, sk0, sk1);
    WAITLGKM();
    g2quad<0, 0, 2>(acc, aL, bL);
    BAR2();
    // ph5
    BAR1();
    g2readA<1>(aH, A1, aro, sk0, sk1);
    WAITLGKM();
    g2quad<1, 0, 2>(acc, aH, bL);
    BAR2();
    // ph6: stage A1<-knh (A1 reads done ph5)
    stageA(knh, A1);
    BAR1();
    g2readB<2, 1>(bH, B1, bro, sk0, sk1);
    WAITLGKM();
    g2quad<1, 2, 1>(acc, aH, bH);
    BAR2();
    // ph7
    BAR1();
    g2quad<0, 2, 1>(acc, aL, bH);
    BAR2();
  }

  // epilogue: fp32 stores; col span 192*4B = whole 128B lines, aligned.
  const int r0 = lq * 4;
#pragma unroll
  for (int mf = 0; mf < 4; ++mf)
#pragma unroll
    for (int nf = 0; nf < 3; ++nf)
#pragma unroll
      for (int r = 0; r < 4; ++r) {
        const size_t row = (size_t)(m0 + wm * 64 + mf * 16 + r0 + r);
        const size_t col = (size_t)(n0 + wn * 48 + nf * 16 + lm);
        C[row * N + col] = acc[mf][nf][r];
      }
}

// ---------------------------------------------------------------------------
// qk RMS-norm + 3D RoPE (V handled by transpose_v).
// ---------------------------------------------------------------------------
static __device__ __forceinline__ float rope_one(float v, float p, int d,
                                                 const float* c3) {
  const int a  = d >> 5;        // which of 3 coord axes (d3=32)
  const int j  = d & 31;
  const int jj = j & 15;        // half=16
  const float invf = fexp2((float)jj * -0.8304820237218406f);
  const float ang  = c3[a] * invf;
  float sn, cs;
  __sincosf(ang, &sn, &cs);
  return (j < 16) ? (v * cs - p * sn) : (v * cs + p * sn);
}

__global__ __launch_bounds__(256) void normrope_kernel(
    const __bf16* __restrict__ qkv, const float* __restrict__ coords,
    const int* __restrict__ ttype, const float* __restrict__ qsc,
    const float* __restrict__ ksc, __bf16* __restrict__ qo,
    __bf16* __restrict__ ko) {
  const int l   = threadIdx.x & 63;
  const int w   = threadIdx.x >> 6;
  const int rid = blockIdx.x * 4 + w;       // (b*T+t)*H + h
  const int h   = rid & (NH - 1);
  const int bt  = rid >> 4;
  const int t   = bt & (NT - 1);
  const int b   = bt >> 11;                 // T = 2048
  const __bf16* base = qkv + (size_t)bt * NQKV + h * ND;
  const float*  c3   = coords + (size_t)bt * 3;
  const bool rope    = ttype[bt] > 0;
  const size_t bh    = (size_t)(b * NH + h);

  // ---- q ----
  {
    float x0 = (float)base[l];
    float x1 = (l < 32) ? (float)base[64 + l] : 0.f;
    float ss = x0 * x0 + x1 * x1;
#pragma unroll
    for (int off = 1; off < 64; off <<= 1) ss += __shfl_xor(ss, off, 64);
    const float rn = rsqrtf(ss * (1.f / 96.f) + 1e-6f);
    x0 *= rn * qsc[l];
    if (l < 32) x1 *= rn * qsc[64 + l];
    const float p0 = __shfl_xor(x0, 16, 64);
    const float p1 = __shfl_xor(x1, 16, 64);
    if (rope) {
      x0 = rope_one(x0, p0, l, c3);
      if (l < 32) x1 = rope_one(x1, p1, 64 + l, c3);
    }
    __bf16* dst = qo + (bh * NT + t) * ND;
    dst[l] = (__bf16)x0;
    if (l < 32) dst[64 + l] = (__bf16)x1;
  }
  // ---- k ----
  {
    float x0 = (float)base[NC + l];
    float x1 = (l < 32) ? (float)base[NC + 64 + l] : 0.f;
    float ss = x0 * x0 + x1 * x1;
#pragma unroll
    for (int off = 1; off < 64; off <<= 1) ss += __shfl_xor(ss, off, 64);
    const float rn = rsqrtf(ss * (1.f / 96.f) + 1e-6f);
    x0 *= rn * ksc[l];
    if (l < 32) x1 *= rn * ksc[64 + l];
    const float p0 = __shfl_xor(x0, 16, 64);
    const float p1 = __shfl_xor(x1, 16, 64);
    if (rope) {
      x0 = rope_one(x0, p0, l, c3);
      if (l < 32) x1 = rope_one(x1, p1, 64 + l, c3);
    }
    __bf16* dst = ko + (bh * NT + t) * ND;
    dst[l] = (__bf16)x0;
    if (l < 32) dst[64 + l] = (__bf16)x1;
  }
}

// ---------------------------------------------------------------------------
// V transpose: qkv V-region (t-major) -> vT (B,H,D,T). LDS-tiled, coalesced
// both sides. Grid (NT/256, NB*NH) = (8,32) = 256 blocks, 256 thr.
// Thread = one t-row: reads 12 x 16B (contiguous 192B run per thread);
// LDS scatter tile[d][t] is conflict-free (lanes span t, 2 lanes/bank);
// write side: b128 LDS reads + 16B global stores in 512B runs per d-row.
// ---------------------------------------------------------------------------
__global__ __launch_bounds__(256) void transpose_v(
    const __bf16* __restrict__ qkv, __bf16* __restrict__ vo) {
  __shared__ __align__(16) __bf16 tile[96][264];   // pad 8 -> 528B row stride
  const int tid = threadIdx.x;
  const int bh  = blockIdx.y;          // b*16+h
  const int t0  = blockIdx.x * 256;
  const int b   = bh >> 4, h = bh & 15;
  const __bf16* src =
      qkv + ((size_t)(b * NT + t0 + tid)) * NQKV + 2 * NC + h * ND;
#pragma unroll
  for (int ch = 0; ch < 12; ++ch) {
    bf16x8 v = *(const bf16x8*)(src + ch * 8);
#pragma unroll
    for (int j = 0; j < 8; ++j) tile[ch * 8 + j][tid] = v[j];
  }
  __syncthreads();
#pragma unroll
  for (int k = 0; k < 12; ++k) {
    const int c  = tid + k * 256;
    const int d  = c >> 5;            // 0..95
    const int tc = c & 31;            // 0..31
    bf16x8 v = *(const bf16x8*)(&tile[d][tc * 8]);
    *(bf16x8*)(vo + ((size_t)bh * ND + d) * NT + t0 + tc * 8) = v;
  }
}

// ---------------------------------------------------------------------------
// Flash attention with LDS-staged K/V, fixed-max softmax. (unchanged)
// ---------------------------------------------------------------------------
static __device__ __forceinline__ void attn_tile(
    const bf16x8 (&aq)[3], const bf16x8 (&bk)[2][3], int q0r, int n0,
    int lm, int lq, f32x4& lsum, __bf16* pbase /* 16 rows x 40 */) {
  f32x4 s[2];
#pragma unroll
  for (int nt = 0; nt < 2; ++nt) {
    f32x4 a = {};
#pragma unroll
    for (int c = 0; c < 3; ++c)
      a = __builtin_amdgcn_mfma_f32_16x16x32_bf16(aq[c], bk[nt][c], a, 0, 0, 0);
    s[nt] = a;
  }
  if (n0 + 31 > q0r) {   // diagonal-straddling tile: causal mask
#pragma unroll
    for (int nt = 0; nt < 2; ++nt)
#pragma unroll
      for (int r = 0; r < 4; ++r)
        if (n0 + nt * 16 + lm > q0r + lq * 4 + r) s[nt][r] = -1e30f;
  }
  const float cl = 0.10206207261596575f * 1.4426950408889634f;
#pragma unroll
  for (int nt = 0; nt < 2; ++nt)
#pragma unroll
    for (int r = 0; r < 4; ++r)
      s[nt][r] = fexp2((s[nt][r] - 96.0f) * cl);
#pragma unroll
  for (int r = 0; r < 4; ++r) lsum[r] += s[0][r] + s[1][r];
#pragma unroll
  for (int nt = 0; nt < 2; ++nt)
#pragma unroll
    for (int r = 0; r < 4; ++r)
      pbase[(lq * 4 + r) * 40 + nt * 16 + lm] = (__bf16)s[nt][r];
}

__global__ __launch_bounds__(512) void attn_fwd2(
    const __bf16* __restrict__ q, const __bf16* __restrict__ k,
    const __bf16* __restrict__ vt, __bf16* __restrict__ out) {
  __shared__ __align__(16) char KV[2][12288];        // [buf][K 6KB | V 6KB]
  __shared__ __align__(16) __bf16 plds[8][2][16][40];
  const int tid = threadIdx.x;
  const int l   = tid & 63;
  const int w   = tid >> 6;          // 0..7
  const int bh  = blockIdx.y;
  const int qp  = blockIdx.x;        // 0..7
  const int lm  = l & 15;
  const int lq  = l >> 4;
  const int q0L = qp * 128 + w * 16;
  const int q0H = (15 - qp) * 128 + w * 16;
  const int nktLw = qp * 4 + (w >> 1) + 1;          // causal tiles, frag L
  const int nktHw = (15 - qp) * 4 + (w >> 1) + 1;   // causal tiles, frag H
  const int nkt   = (15 - qp) * 4 + 4;              // block loop bound
  const __bf16* qh = q  + (size_t)bh * NT * ND;
  const __bf16* kh = k  + (size_t)bh * NT * ND;
  const __bf16* vh = vt + (size_t)bh * ND * NT;
  __bf16* pbL = &plds[w][0][0][0];
  __bf16* pbH = &plds[w][1][0][0];

  auto stage = [&](int n0, char* buf) {
    if (w < 6) {
      const int nt = w / 3, c = w - nt * 3;
      g2lds16(kh + (size_t)(n0 + nt * 16 + (l >> 2)) * ND + c * 32 + (l & 3) * 8,
              buf + w * 1024);
    } else {
      const int v = w - 6;
      g2lds16(vh + (size_t)(v * 16 + (l >> 2)) * NT + n0 + (l & 3) * 8,
              buf + 6144 + v * 1024);
    }
    if (w < 4) {
      const int v = 2 + w;
      g2lds16(vh + (size_t)(v * 16 + (l >> 2)) * NT + n0 + (l & 3) * 8,
              buf + 6144 + v * 1024);
    }
  };

  bf16x8 aqL[3], aqH[3];
#pragma unroll
  for (int c = 0; c < 3; ++c) {
    aqL[c] = *(const bf16x8*)(qh + (size_t)(q0L + lm) * ND + c * 32 + lq * 8);
    aqH[c] = *(const bf16x8*)(qh + (size_t)(q0H + lm) * ND + c * 32 + lq * 8);
  }

  f32x4 oL[6] = {}, oH[6] = {};
  f32x4 lsL = {}, lsH = {};
  const int ji = (lm * 4 + lq) * 16;   // this lane's chunk byte offset

  stage(0, KV[0]);
  for (int kt = 0; kt < nkt; ++kt) {
    __syncthreads();                   // drains stage(kt); all waves done kt-1
    if (kt + 1 < nkt) stage((kt + 1) * 32, KV[(kt + 1) & 1]);
    const char* Kc = KV[kt & 1];
    const char* Vc = KV[kt & 1] + 6144;
    const int n0 = kt * 32;
    bf16x8 bk[2][3];
#pragma unroll
    for (int nt = 0; nt < 2; ++nt)
#pragma unroll
      for (int c = 0; c < 3; ++c)
        bk[nt][c] = *(const bf16x8*)(Kc + (nt * 3 + c) * 1024 + ji);
    const bool doL = kt < nktLw;       // wave-uniform
    const bool doH = kt < nktHw;
    if (doL) attn_tile(aqL, bk, q0L, n0, lm, lq, lsL, pbL);
    if (doH) attn_tile(aqH, bk, q0H, n0, lm, lq, lsH, pbH);
    bf16x8 apL = {}, apH = {};
    if (doL) apL = *(const bf16x8*)(pbL + lm * 40 + lq * 8);
    if (doH) apH = *(const bf16x8*)(pbH + lm * 40 + lq * 8);
#pragma unroll
    for (int dt = 0; dt < 6; ++dt) {
      bf16x8 bv = *(const bf16x8*)(Vc + dt * 1024 + ji);
      if (doL) oL[dt] = __builtin_amdgcn_mfma_f32_16x16x32_bf16(apL, bv, oL[dt], 0, 0, 0);
      if (doH) oH[dt] = __builtin_amdgcn_mfma_f32_16x16x32_bf16(apH, bv, oH[dt], 0, 0, 0);
    }
  }

  // epilogue: out[(b*T+t), h*96+d] for both frags
  const int b = bh >> 4, h = bh & 15;
#pragma unroll
  for (int f = 0; f < 2; ++f) {
    const f32x4* o = f ? oH : oL;
    const f32x4& ls = f ? lsH : lsL;
    const int q0 = f ? q0H : q0L;
    float rl[4];
#pragma unroll
    for (int r = 0; r < 4; ++r) {
      float v = ls[r];
#pragma unroll
      for (int off = 1; off < 16; off <<= 1) v += __shfl_xor(v, off, 64);
      rl[r] = 1.f / v;
    }
#pragma unroll
    for (int dt = 0; dt < 6; ++dt)
#pragma unroll
      for (int r = 0; r < 4; ++r) {
        const int t = q0 + lq * 4 + r;
        out[((size_t)(b * NT + t)) * NC + h * ND + dt * 16 + lm] =
            (__bf16)(o[dt][r] * rl[r]);
      }
  }
}

// ---------------------------------------------------------------------------
// workspace layout (bytes); attn-out aliases xb (dead after GEMM1)
// ---------------------------------------------------------------------------
static constexpr size_t OFF_XB   = 0;          // 12,582,912  (also attn out)
static constexpr size_t OFF_WQKV = 12582912;   // 14,155,776
static constexpr size_t OFF_WOUT = 26738688;   //  4,718,592
static constexpr size_t OFF_QKV  = 31457280;   // 37,748,736
static constexpr size_t OFF_Q    = 69206016;   // 12,582,912
static constexpr size_t OFF_K    = 81788928;   // 12,582,912
static constexpr size_t OFF_VT   = 94371840;   // 12,582,912  -> end 106,954,752

extern "C" void kernel_launch(void* const* d_in, const int* in_sizes, int n_in,
                              void* d_out, int out_size, void* d_ws,
                              size_t ws_size, hipStream_t stream) {
  const float* x      = (const float*)d_in[0];
  const float* coords = (const float*)d_in[1];
  const int*   ttype  = (const int*)d_in[2];
  const float* wqkv   = (const float*)d_in[3];
  const float* wout   = (const float*)d_in[4];
  const float* qs     = (const float*)d_in[5];
  const float* ks     = (const float*)d_in[6];

  char* ws = (char*)d_ws;
  __bf16* xb    = (__bf16*)(ws + OFF_XB);
  __bf16* wqkvb = (__bf16*)(ws + OFF_WQKV);
  __bf16* woutb = (__bf16*)(ws + OFF_WOUT);
  __bf16* qkvb  = (__bf16*)(ws + OFF_QKV);
  __bf16* qb    = (__bf16*)(ws + OFF_Q);
  __bf16* kb    = (__bf16*)(ws + OFF_K);
  __bf16* vtb   = (__bf16*)(ws + OFF_VT);
  __bf16* attnb = (__bf16*)(ws + OFF_XB);   // alias

  // 1. fp32 -> bf16 conversions
  {
    const int n4x = NM * NC / 4;            // 1,572,864
    const int n4w = NQKV * NC / 4;          // 1,769,472
    const int n4o = NC * NC / 4;            //   589,824
    cvt_f32_bf16<<<(n4x + 255) / 256, 256, 0, stream>>>(
        (const float4*)x, (bf16x4*)xb, n4x);
    cvt_f32_bf16<<<(n4w + 255) / 256, 256, 0, stream>>>(
        (const float4*)wqkv, (bf16x4*)wqkvb, n4w);
    cvt_f32_bf16<<<(n4o + 255) / 256, 256, 0, stream>>>(
        (const float4*)wout, (bf16x4*)woutb, n4o);
  }
  // 2. qkv = x @ W_qkv^T  (bf16 out, 256x288 8-phase, grid 16x16=256)
  gemm1_8ph<<<dim3(NQKV / 288, NM / 256), 512, 0, stream>>>(
      xb, wqkvb, qkvb, NM, NQKV, NC);
  // 3. qk-norm + rope; V transpose (separate, LDS-tiled)
  normrope_kernel<<<(NB * NT * NH) / 4, 256, 0, stream>>>(
      qkvb, coords, ttype, qs, ks, qb, kb);
  transpose_v<<<dim3(NT / 256, NB * NH), 256, 0, stream>>>(qkvb, vtb);
  // 4. causal attention (LDS-staged K/V, mirrored q-pairs)
  attn_fwd2<<<dim3(8, NB * NH), 512, 0, stream>>>(qb, kb, vtb, attnb);
  // 5. out = attn @ W_out^T (fp32 out, 128x192 8-phase, grid 8x32=256)
  gemm2_8ph<<<dim3(NC / 192, NM / 128), 512, 0, stream>>>(
      attnb, woutb, (float*)d_out, NM, NC, NC);
}